// Round 2
// baseline (309.345 us; speedup 1.0000x reference)
//
#include <hip/hip_runtime.h>
#include <math.h>

typedef unsigned long long u64;
typedef unsigned int u32;

#define B_ 2
#define F_ 8
#define P_ 2048
#define T_ 7                   // F-1
#define ROWS (B_*T_*P_)        // 28672

// ---- keys as positive-normal doubles: bit pattern 0x4000.. | ou<<16 | idx ----
// for positive doubles, IEEE ordering == integer ordering of the bit pattern,
// so compare-exchange = v_min_f64 + v_max_f64 (2 ops vs 5 for u64).
__device__ __forceinline__ double pack_key(u32 ou, u32 idx) {
  u64 bits = 0x4000000000000000ull | ((u64)ou << 16) | idx;
  return __longlong_as_double((long long)bits);
}

#define CED(arr,a,b) do { double _x=arr[a], _y=arr[b]; arr[a]=fmin(_x,_y); arr[b]=fmax(_x,_y); } while(0)

// Batcher odd-even mergesort, 8 elements, 19 comparators
__device__ __forceinline__ void sort8d(double* k) {
  CED(k,0,1); CED(k,2,3); CED(k,4,5); CED(k,6,7);
  CED(k,0,2); CED(k,1,3); CED(k,4,6); CED(k,5,7);
  CED(k,1,2); CED(k,5,6);
  CED(k,0,4); CED(k,1,5); CED(k,2,6); CED(k,3,7);
  CED(k,2,4); CED(k,3,5);
  CED(k,1,2); CED(k,3,4); CED(k,5,6);
}

// A,B sorted ascending -> A = lowest 8 of the 16, sorted
__device__ __forceinline__ void low8(double* A, const double* Bv) {
#pragma unroll
  for (int i = 0; i < 8; ++i) A[i] = fmin(A[i], Bv[7-i]);   // bitonic
#pragma unroll
  for (int st = 4; st >= 1; st >>= 1) {
#pragma unroll
    for (int i = 0; i < 8; ++i) {
      if ((i & st) == 0) { CED(A, i, i + st); }
    }
  }
}

// ---------------- Kernel A: bearing quaternions + |q|^2 prepack ----------------
__global__ __launch_bounds__(256) void kA_bearing(const float4* __restrict__ pts,
                                                  float4* __restrict__ bq,
                                                  float4* __restrict__ pts2) {
  int bf = blockIdx.x;                // b*F + f
  const float4* base = pts + (size_t)bf * P_;
  int tid = threadIdx.x;
  float x[8], y[8], z[8];
  float mnx =  INFINITY, mny =  INFINITY, mnz =  INFINITY;
  float mxx = -INFINITY, mxy = -INFINITY, mxz = -INFINITY;
#pragma unroll
  for (int i = 0; i < 8; ++i) {
    float4 v = base[tid + i*256];
    x[i]=v.x; y[i]=v.y; z[i]=v.z;
    mnx=fminf(mnx,v.x); mny=fminf(mny,v.y); mnz=fminf(mnz,v.z);
    mxx=fmaxf(mxx,v.x); mxy=fmaxf(mxy,v.y); mxz=fmaxf(mxz,v.z);
  }
#pragma unroll
  for (int off = 32; off >= 1; off >>= 1) {
    mnx=fminf(mnx,__shfl_xor(mnx,off)); mny=fminf(mny,__shfl_xor(mny,off)); mnz=fminf(mnz,__shfl_xor(mnz,off));
    mxx=fmaxf(mxx,__shfl_xor(mxx,off)); mxy=fmaxf(mxy,__shfl_xor(mxy,off)); mxz=fmaxf(mxz,__shfl_xor(mxz,off));
  }
  __shared__ float red[4][6];
  int wid = tid >> 6, lane = tid & 63;
  if (lane == 0) { red[wid][0]=mnx; red[wid][1]=mny; red[wid][2]=mnz;
                   red[wid][3]=mxx; red[wid][4]=mxy; red[wid][5]=mxz; }
  __syncthreads();
  mnx=fminf(fminf(red[0][0],red[1][0]),fminf(red[2][0],red[3][0]));
  mny=fminf(fminf(red[0][1],red[1][1]),fminf(red[2][1],red[3][1]));
  mnz=fminf(fminf(red[0][2],red[1][2]),fminf(red[2][2],red[3][2]));
  mxx=fmaxf(fmaxf(red[0][3],red[1][3]),fmaxf(red[2][3],red[3][3]));
  mxy=fmaxf(fmaxf(red[0][4],red[1][4]),fmaxf(red[2][4],red[3][4]));
  mxz=fmaxf(fmaxf(red[0][5],red[1][5]),fmaxf(red[2][5],red[3][5]));
  float cx=(mnx+mxx)*0.5f, cy=(mny+mxy)*0.5f, cz=(mnz+mxz)*0.5f;
#pragma unroll
  for (int i = 0; i < 8; ++i) {
    float dx=x[i]-cx, dy=y[i]-cy, dz=z[i]-cz;
    float n = sqrtf(((dx*dx) + dy*dy) + dz*dz);
    n = fmaxf(n, 1e-12f);
    float dxn = dx/n, dyn = dy/n, dzn = dz/n;
    float dotc = fminf(fmaxf(dyn, -0.99999990f), 0.99999990f);
    float half = acosf(dotc) * 0.5f;
    float an = sqrtf(dzn*dzn + dxn*dxn);
    an = fmaxf(an, 1e-12f);
    float axx = dzn/an, axz = (-dxn)/an;
    float s = sinf(half), w = cosf(half);
    bq[(size_t)bf*P_ + tid + i*256] = make_float4(w, axx*s, 0.f, axz*s);
    float qs = fmaf(x[i],x[i], fmaf(y[i],y[i], z[i]*z[i]));
    pts2[(size_t)bf*P_ + tid + i*256] = make_float4(x[i], y[i], z[i], qs);
  }
}

// ---------------- Kernel B: forward quaternions ----------------
__global__ __launch_bounds__(256) void kB_qfwd(const float4* __restrict__ bq,
                                               float4* __restrict__ qf) {
  int i = blockIdx.x*256 + threadIdx.x;   // over B*T*P
  int p = i & (P_-1);
  int t = (i >> 11) % T_;
  int b = i / (T_*P_);
  float4 s = bq[((size_t)(b*F_ + t))*P_ + p];       // frame t (src)
  float4 a = bq[((size_t)(b*F_ + t + 1))*P_ + p];   // frame t+1 (tgt)
  float aw=a.x, ax=a.y, ay=a.z, az=a.w;
  float bw=s.x, bx=-s.y, by=-s.z, bz=-s.w;          // conj
  float w  = ((aw*bw - ax*bx) - ay*by) - az*bz;
  float xo = ((aw*bx + ax*bw) + ay*bz) - az*by;
  float yo = ((aw*by - ax*bz) + ay*bw) + az*bx;
  float zo = ((aw*bz + ax*by) - ay*bx) + az*bw;
  float n = sqrtf(((w*w + xo*xo) + yo*yo) + zo*zo);
  n = fmaxf(n, 1e-12f);
  qf[i] = make_float4(w/n, xo/n, yo/n, zo/n);
}

// ---------------- Kernel C: top-40 selection + geo sums ----------------
__device__ __forceinline__ double makekey(const float4* __restrict__ pbase, int q,
                                          float px, float py, float pz, float ps) {
  float4 c = pbase[q];                 // .w = |c|^2 precomputed with same fma form
  float dot = fmaf(px, c.x, fmaf(py, c.y, pz*c.z));
  float v = (2.f*dot - ps) - c.w;      // = reference neg_dist
  float nd = -v;                       // ascending distance
  u32 u = __float_as_uint(nd);
  u32 ou = (u & 0x80000000u) ? ~u : (u | 0x80000000u);
  return pack_key(ou, (u32)q);
}

__global__ __launch_bounds__(256) void kC_select(const float4* __restrict__ pts2,
                                                 const float4* __restrict__ qf,
                                                 float* __restrict__ S) {
  int wid  = threadIdx.x >> 6;
  int lane = threadIdx.x & 63;
  int row  = blockIdx.x*4 + wid;       // (b*7+t)*2048 + p
  int p  = row & (P_-1);
  int bt = row >> 11;                  // b*7 + t
  int t  = bt % T_;
  int b  = bt / T_;
  const float4* pbase = pts2 + (size_t)(b*F_ + t) * P_;
  float4 pw = pbase[p];
  float px = pw.x, py = pw.y, pz = pw.z;
  float ps = pw.w;

  double A[8], Bv[8], C[8];
#pragma unroll
  for (int s = 0; s < 8; ++s) A[s]  = makekey(pbase, s*64 + lane, px,py,pz,ps);
  sort8d(A);
#pragma unroll
  for (int s = 0; s < 8; ++s) Bv[s] = makekey(pbase, (8+s)*64 + lane, px,py,pz,ps);
  sort8d(Bv);
  low8(A, Bv);                         // A = top-8 of first 16
#pragma unroll
  for (int s = 0; s < 8; ++s) Bv[s] = makekey(pbase, (16+s)*64 + lane, px,py,pz,ps);
  sort8d(Bv);
#pragma unroll
  for (int s = 0; s < 8; ++s) C[s]  = makekey(pbase, (24+s)*64 + lane, px,py,pz,ps);
  sort8d(C);
  low8(Bv, C);                         // Bv = top-8 of last 16
  low8(A, Bv);                         // A = lane-local sorted top-8 of 32

  __shared__ double cache[4][8*64];
  double* mc = cache[wid];
#pragma unroll
  for (int j = 0; j < 8; ++j) mc[j*64 + lane] = A[j];
  // waves are independent: no barrier needed

  double h = A[0];
  int ptr = 0;
  double myKey = 0.0;
  for (int i = 0; i < 40; ++i) {
    double m = h;
#pragma unroll
    for (int off = 32; off >= 1; off >>= 1) m = fmin(m, __shfl_xor(m, off));
    myKey = (lane == i) ? m : myKey;
    if (h == m) {                      // unique keys -> exactly one winner
      ++ptr;
      if (ptr < 8) {
        h = mc[ptr*64 + lane];
      } else {
        // exact refill (rare): smallest of my 32 keys strictly greater than m
        double best = __builtin_huge_val();
#pragma unroll
        for (int s2 = 0; s2 < 32; ++s2) {
          double kk = makekey(pbase, s2*64 + lane, px,py,pz,ps);
          if (kk > m && kk < best) best = kk;
        }
        h = best;
      }
    }
  }

  float4 qp = qf[row];
  float geo = 0.f;
  if (lane < 40) {
    int nb = (int)((u32)((u64)__double_as_longlong(myKey)) & 0xffffu);
    float4 nq = qf[(size_t)bt * P_ + nb];
    float d4 = ((qp.x*nq.x + qp.y*nq.y) + qp.z*nq.z) + qp.w*nq.w;
    float dc = fminf(fabsf(d4), 0.99999990f);
    geo = 2.f * acosf(dc);
  }
  float g40 = geo;
  float g15 = (lane < 15) ? geo : 0.f;
  float g5  = (lane < 5)  ? geo : 0.f;
#pragma unroll
  for (int off = 32; off >= 1; off >>= 1) {
    g40 += __shfl_xor(g40, off);
    g15 += __shfl_xor(g15, off);
    g5  += __shfl_xor(g5,  off);
  }
  if (lane == 0) {
    S[0*ROWS + row] = g5  / 5.f;
    S[1*ROWS + row] = g15 / 15.f;
    S[2*ROWS + row] = g40 / 40.f;
  }
}

// ---------------- Kernel E: mean over t, median, output ----------------
__global__ __launch_bounds__(1024) void kE_final(const float* __restrict__ S,
                                                 float* __restrict__ out) {
  int k = blockIdx.x;                  // scale index 0..2
  int tid = threadIdx.x;
  __shared__ float srt[4096];
  const float* Sk = S + (size_t)k * ROWS;
  float m[4];
#pragma unroll
  for (int u = 0; u < 4; ++u) {
    int j = tid + u*1024;              // j = b*2048 + p
    int b = j >> 11, p = j & 2047;
    float acc = 0.f;
#pragma unroll
    for (int t = 0; t < 7; ++t) acc += Sk[(b*7 + t)*2048 + p];
    m[u] = acc / 7.f;
    srt[j] = m[u];
  }
  __syncthreads();
  for (int size = 2; size <= 4096; size <<= 1) {
    for (int stride = size >> 1; stride > 0; stride >>= 1) {
      for (int c = tid; c < 2048; c += 1024) {
        int i = 2*c - (c & (stride - 1));
        int j = i + stride;
        bool up = ((i & size) == 0);
        float a = srt[i], bb = srt[j];
        if ((a > bb) == up) { srt[i] = bb; srt[j] = a; }
      }
      __syncthreads();
    }
  }
  float scale = fmaxf(srt[2047], 1e-6f);   // lower median of 4096
  bool pos = srt[4095] > 0.f;
#pragma unroll
  for (int u = 0; u < 4; ++u) {
    int j = tid + u*1024;
    int b = j >> 11, p = j & 2047;
    float r = pos ? expf(-m[u]/scale) : 1.f;
    float* ob = out + ((size_t)(b*3 + k)*8)*2048 + p;
#pragma unroll
    for (int f = 0; f < 8; ++f) ob[f*2048] = r;
  }
}

extern "C" void kernel_launch(void* const* d_in, const int* in_sizes, int n_in,
                              void* d_out, int out_size, void* d_ws, size_t ws_size,
                              hipStream_t stream) {
  (void)in_sizes; (void)n_in; (void)out_size; (void)ws_size;
  const float4* pts = (const float4*)d_in[0];
  float* ws = (float*)d_ws;
  float4* bq   = (float4*)ws;                     // B*F*P*4   = 131072 floats
  float4* qfw  = (float4*)(ws + 131072);          // B*T*P*4   = 114688 floats
  float*  S    = ws + 131072 + 114688;            // 3*ROWS    =  86016 floats
  float4* pts2 = (float4*)(ws + 131072 + 114688 + 86016);  // B*F*P*4 = 131072 floats
  float*  out = (float*)d_out;

  hipLaunchKernelGGL(kA_bearing, dim3(B_*F_), dim3(256), 0, stream, pts, bq, pts2);
  hipLaunchKernelGGL(kB_qfwd,    dim3(ROWS/256), dim3(256), 0, stream, bq, qfw);
  hipLaunchKernelGGL(kC_select,  dim3(ROWS/4), dim3(256), 0, stream, pts2, qfw, S);
  hipLaunchKernelGGL(kE_final,   dim3(3), dim3(1024), 0, stream, S, out);
}

// Round 3
// 234.900 us; speedup vs baseline: 1.3169x; 1.3169x over previous
//
#include <hip/hip_runtime.h>
#include <math.h>

typedef unsigned long long u64;
typedef unsigned int u32;

#define B_ 2
#define F_ 8
#define P_ 2048
#define T_ 7                   // F-1
#define ROWS (B_*T_*P_)        // 28672
#define SENT_OU 0xFFFFFFFFu

// ---- keys as positive-normal doubles: bit pattern 0x4000.. | ou<<16 | idx ----
// for positive doubles, IEEE ordering == integer ordering of the bit pattern,
// so compare-exchange = v_min_f64 + v_max_f64 (2 ops vs 5 for u64).
__device__ __forceinline__ double pack_key(u32 ou, u32 idx) {
  u64 bits = 0x4000000000000000ull | ((u64)ou << 16) | idx;
  return __longlong_as_double((long long)bits);
}

#define CED(arr,a,b) do { double _x=arr[a], _y=arr[b]; arr[a]=fmin(_x,_y); arr[b]=fmax(_x,_y); } while(0)

// Batcher odd-even mergesort, 8 elements, 19 comparators
__device__ __forceinline__ void sort8d(double* k) {
  CED(k,0,1); CED(k,2,3); CED(k,4,5); CED(k,6,7);
  CED(k,0,2); CED(k,1,3); CED(k,4,6); CED(k,5,7);
  CED(k,1,2); CED(k,5,6);
  CED(k,0,4); CED(k,1,5); CED(k,2,6); CED(k,3,7);
  CED(k,2,4); CED(k,3,5);
  CED(k,1,2); CED(k,3,4); CED(k,5,6);
}

// A,B sorted ascending -> A = lowest 8 of the 16, sorted
__device__ __forceinline__ void low8(double* A, const double* Bv) {
#pragma unroll
  for (int i = 0; i < 8; ++i) A[i] = fmin(A[i], Bv[7-i]);   // bitonic
#pragma unroll
  for (int st = 4; st >= 1; st >>= 1) {
#pragma unroll
    for (int i = 0; i < 8; ++i) {
      if ((i & st) == 0) { CED(A, i, i + st); }
    }
  }
}

// ---- DPP wave64 reductions (no LDS/DS): canonical shr1/2/4/8 + bcast15/31 ----
// result valid in lane 63.
__device__ __forceinline__ u32 dpp_min_u32(u32 x) {
  u32 t;
  t = (u32)__builtin_amdgcn_update_dpp((int)x,(int)x,0x111,0xf,0xf,false); x = t<x?t:x;
  t = (u32)__builtin_amdgcn_update_dpp((int)x,(int)x,0x112,0xf,0xf,false); x = t<x?t:x;
  t = (u32)__builtin_amdgcn_update_dpp((int)x,(int)x,0x114,0xf,0xf,false); x = t<x?t:x;
  t = (u32)__builtin_amdgcn_update_dpp((int)x,(int)x,0x118,0xf,0xf,false); x = t<x?t:x;
  t = (u32)__builtin_amdgcn_update_dpp((int)x,(int)x,0x142,0xf,0xf,false); x = t<x?t:x;
  t = (u32)__builtin_amdgcn_update_dpp((int)x,(int)x,0x143,0xf,0xf,false); x = t<x?t:x;
  return x;
}
__device__ __forceinline__ float dpp_sum_f32(float x) {
  float t;
  t = __uint_as_float((u32)__builtin_amdgcn_update_dpp(0,(int)__float_as_uint(x),0x111,0xf,0xf,false)); x += t;
  t = __uint_as_float((u32)__builtin_amdgcn_update_dpp(0,(int)__float_as_uint(x),0x112,0xf,0xf,false)); x += t;
  t = __uint_as_float((u32)__builtin_amdgcn_update_dpp(0,(int)__float_as_uint(x),0x114,0xf,0xf,false)); x += t;
  t = __uint_as_float((u32)__builtin_amdgcn_update_dpp(0,(int)__float_as_uint(x),0x118,0xf,0xf,false)); x += t;
  t = __uint_as_float((u32)__builtin_amdgcn_update_dpp(0,(int)__float_as_uint(x),0x142,0xf,0xf,false)); x += t;
  t = __uint_as_float((u32)__builtin_amdgcn_update_dpp(0,(int)__float_as_uint(x),0x143,0xf,0xf,false)); x += t;
  return x;
}

// ---------------- Kernel A: bearing quaternions + |q|^2 prepack ----------------
__global__ __launch_bounds__(256) void kA_bearing(const float4* __restrict__ pts,
                                                  float4* __restrict__ bq,
                                                  float4* __restrict__ pts2) {
  int bf = blockIdx.x;                // b*F + f
  const float4* base = pts + (size_t)bf * P_;
  int tid = threadIdx.x;
  float x[8], y[8], z[8];
  float mnx =  INFINITY, mny =  INFINITY, mnz =  INFINITY;
  float mxx = -INFINITY, mxy = -INFINITY, mxz = -INFINITY;
#pragma unroll
  for (int i = 0; i < 8; ++i) {
    float4 v = base[tid + i*256];
    x[i]=v.x; y[i]=v.y; z[i]=v.z;
    mnx=fminf(mnx,v.x); mny=fminf(mny,v.y); mnz=fminf(mnz,v.z);
    mxx=fmaxf(mxx,v.x); mxy=fmaxf(mxy,v.y); mxz=fmaxf(mxz,v.z);
  }
#pragma unroll
  for (int off = 32; off >= 1; off >>= 1) {
    mnx=fminf(mnx,__shfl_xor(mnx,off)); mny=fminf(mny,__shfl_xor(mny,off)); mnz=fminf(mnz,__shfl_xor(mnz,off));
    mxx=fmaxf(mxx,__shfl_xor(mxx,off)); mxy=fmaxf(mxy,__shfl_xor(mxy,off)); mxz=fmaxf(mxz,__shfl_xor(mxz,off));
  }
  __shared__ float red[4][6];
  int wid = tid >> 6, lane = tid & 63;
  if (lane == 0) { red[wid][0]=mnx; red[wid][1]=mny; red[wid][2]=mnz;
                   red[wid][3]=mxx; red[wid][4]=mxy; red[wid][5]=mxz; }
  __syncthreads();
  mnx=fminf(fminf(red[0][0],red[1][0]),fminf(red[2][0],red[3][0]));
  mny=fminf(fminf(red[0][1],red[1][1]),fminf(red[2][1],red[3][1]));
  mnz=fminf(fminf(red[0][2],red[1][2]),fminf(red[2][2],red[3][2]));
  mxx=fmaxf(fmaxf(red[0][3],red[1][3]),fmaxf(red[2][3],red[3][3]));
  mxy=fmaxf(fmaxf(red[0][4],red[1][4]),fmaxf(red[2][4],red[3][4]));
  mxz=fmaxf(fmaxf(red[0][5],red[1][5]),fmaxf(red[2][5],red[3][5]));
  float cx=(mnx+mxx)*0.5f, cy=(mny+mxy)*0.5f, cz=(mnz+mxz)*0.5f;
#pragma unroll
  for (int i = 0; i < 8; ++i) {
    float dx=x[i]-cx, dy=y[i]-cy, dz=z[i]-cz;
    float n = sqrtf(((dx*dx) + dy*dy) + dz*dz);
    n = fmaxf(n, 1e-12f);
    float dxn = dx/n, dyn = dy/n, dzn = dz/n;
    float dotc = fminf(fmaxf(dyn, -0.99999990f), 0.99999990f);
    float half = acosf(dotc) * 0.5f;
    float an = sqrtf(dzn*dzn + dxn*dxn);
    an = fmaxf(an, 1e-12f);
    float axx = dzn/an, axz = (-dxn)/an;
    float s = sinf(half), w = cosf(half);
    bq[(size_t)bf*P_ + tid + i*256] = make_float4(w, axx*s, 0.f, axz*s);
    float qs = fmaf(x[i],x[i], fmaf(y[i],y[i], z[i]*z[i]));
    pts2[(size_t)bf*P_ + tid + i*256] = make_float4(x[i], y[i], z[i], qs);
  }
}

// ---------------- Kernel B: forward quaternions ----------------
__global__ __launch_bounds__(256) void kB_qfwd(const float4* __restrict__ bq,
                                               float4* __restrict__ qf) {
  int i = blockIdx.x*256 + threadIdx.x;   // over B*T*P
  int p = i & (P_-1);
  int t = (i >> 11) % T_;
  int b = i / (T_*P_);
  float4 s = bq[((size_t)(b*F_ + t))*P_ + p];       // frame t (src)
  float4 a = bq[((size_t)(b*F_ + t + 1))*P_ + p];   // frame t+1 (tgt)
  float aw=a.x, ax=a.y, ay=a.z, az=a.w;
  float bw=s.x, bx=-s.y, by=-s.z, bz=-s.w;          // conj
  float w  = ((aw*bw - ax*bx) - ay*by) - az*bz;
  float xo = ((aw*bx + ax*bw) + ay*bz) - az*by;
  float yo = ((aw*by - ax*bz) + ay*bw) + az*bx;
  float zo = ((aw*bz + ax*by) - ay*bx) + az*bw;
  float n = sqrtf(((w*w + xo*xo) + yo*yo) + zo*zo);
  n = fmaxf(n, 1e-12f);
  qf[i] = make_float4(w/n, xo/n, yo/n, zo/n);
}

// ---------------- Kernel C: top-40 selection + geo sums ----------------
__device__ __forceinline__ double makekey(const float4* __restrict__ pbase, int q,
                                          float px, float py, float pz, float ps) {
  float4 c = pbase[q];                 // .w = |c|^2 precomputed with same fma form
  float dot = fmaf(px, c.x, fmaf(py, c.y, pz*c.z));
  float v = (2.f*dot - ps) - c.w;      // = reference neg_dist
  float nd = -v;                       // ascending distance
  u32 u = __float_as_uint(nd);
  u32 ou = (u & 0x80000000u) ? ~u : (u | 0x80000000u);
  return pack_key(ou, (u32)q);
}

__global__ __launch_bounds__(256) void kC_select(const float4* __restrict__ pts2,
                                                 const float4* __restrict__ qf,
                                                 float* __restrict__ S) {
  int wid  = threadIdx.x >> 6;
  int lane = threadIdx.x & 63;
  int row  = blockIdx.x*4 + wid;       // (b*7+t)*2048 + p
  int p  = row & (P_-1);
  int bt = row >> 11;                  // b*7 + t
  int t  = bt % T_;
  int b  = bt / T_;
  const float4* pbase = pts2 + (size_t)(b*F_ + t) * P_;
  float4 pw = pbase[p];
  float px = pw.x, py = pw.y, pz = pw.z;
  float ps = pw.w;

  double A[8], Bv[8], C[8];
#pragma unroll
  for (int s = 0; s < 8; ++s) A[s]  = makekey(pbase, s*64 + lane, px,py,pz,ps);
  sort8d(A);
#pragma unroll
  for (int s = 0; s < 8; ++s) Bv[s] = makekey(pbase, (8+s)*64 + lane, px,py,pz,ps);
  sort8d(Bv);
  low8(A, Bv);                         // A = top-8 of first 16
#pragma unroll
  for (int s = 0; s < 8; ++s) Bv[s] = makekey(pbase, (16+s)*64 + lane, px,py,pz,ps);
  sort8d(Bv);
#pragma unroll
  for (int s = 0; s < 8; ++s) C[s]  = makekey(pbase, (24+s)*64 + lane, px,py,pz,ps);
  sort8d(C);
  low8(Bv, C);                         // Bv = top-8 of last 16
  low8(A, Bv);                         // A = lane-local sorted top-8 of 32

  // unpack into register shift-queue (all static indices -> stays in VGPRs)
  u32 OU[8], IDX[8];
#pragma unroll
  for (int j = 0; j < 8; ++j) {
    u64 bits = (u64)__double_as_longlong(A[j]);
    OU[j]  = (u32)(bits >> 16);
    IDX[j] = (u32)(bits & 0xffffu);
  }

  u32 last_ou = 0, last_idx = 0;       // last key popped by THIS lane
  u32 cap_idx = 0;                     // lane i captures the i-th popped neighbor idx

#pragma unroll 1
  for (int i = 0; i < 40; ++i) {
    // exact refill: a lane whose 8-deep queue is exhausted recomputes its true
    // next candidate (wave-uniform branch, ~never taken)
    if (__any(OU[0] == SENT_OU)) {
      bool need = (OU[0] == SENT_OU);
      double lastK = pack_key(last_ou, last_idx);
      double best = __builtin_huge_val();
#pragma unroll
      for (int s2 = 0; s2 < 32; ++s2) {
        double kk = makekey(pbase, s2*64 + lane, px,py,pz,ps);
        best = (kk > lastK && kk < best) ? kk : best;
      }
      if (need) {
        if (best < __builtin_huge_val()) {
          u64 bb = (u64)__double_as_longlong(best);
          OU[0]  = (u32)(bb >> 16);
          IDX[0] = (u32)(bb & 0xffffu);
        }                               // else truly exhausted: stays SENT
      }
    }

    u32 m = dpp_min_u32(OU[0]);
    u32 s_min = (u32)__builtin_amdgcn_readlane(m, 63);
    u64 mk = __ballot(OU[0] == s_min);
    u32 s_idx;
    if (__popcll(mk) == 1) {
      s_idx = (u32)__builtin_amdgcn_readlane(IDX[0], (int)__builtin_ctzll(mk));
    } else {                            // distance tie across lanes: lowest idx wins
      u32 tt = (OU[0] == s_min) ? IDX[0] : 0xFFFFFFFFu;
      s_idx = (u32)__builtin_amdgcn_readlane(dpp_min_u32(tt), 63);
    }
    cap_idx = (lane == i) ? s_idx : cap_idx;

    bool iam = (OU[0] == s_min) && (IDX[0] == s_idx);
    last_ou  = iam ? s_min : last_ou;
    last_idx = iam ? s_idx : last_idx;
#pragma unroll
    for (int j = 0; j < 7; ++j) {
      OU[j]  = iam ? OU[j+1]  : OU[j];
      IDX[j] = iam ? IDX[j+1] : IDX[j];
    }
    OU[7] = iam ? SENT_OU : OU[7];
  }

  float4 qp = qf[row];
  float geo = 0.f;
  if (lane < 40) {
    float4 nq = qf[(size_t)bt * P_ + cap_idx];
    float d4 = ((qp.x*nq.x + qp.y*nq.y) + qp.z*nq.z) + qp.w*nq.w;
    float dc = fminf(fabsf(d4), 0.99999990f);
    geo = 2.f * acosf(dc);
  }
  float g40 = dpp_sum_f32(geo);
  float g15 = dpp_sum_f32((lane < 15) ? geo : 0.f);
  float g5  = dpp_sum_f32((lane < 5)  ? geo : 0.f);
  if (lane == 63) {
    S[0*ROWS + row] = g5  / 5.f;
    S[1*ROWS + row] = g15 / 15.f;
    S[2*ROWS + row] = g40 / 40.f;
  }
}

// ---------------- Kernel E: mean over t, median, output ----------------
__global__ __launch_bounds__(1024) void kE_final(const float* __restrict__ S,
                                                 float* __restrict__ out) {
  int k = blockIdx.x;                  // scale index 0..2
  int tid = threadIdx.x;
  __shared__ float srt[4096];
  const float* Sk = S + (size_t)k * ROWS;
  float m[4];
#pragma unroll
  for (int u = 0; u < 4; ++u) {
    int j = tid + u*1024;              // j = b*2048 + p
    int b = j >> 11, p = j & 2047;
    float acc = 0.f;
#pragma unroll
    for (int t = 0; t < 7; ++t) acc += Sk[(b*7 + t)*2048 + p];
    m[u] = acc / 7.f;
    srt[j] = m[u];
  }
  __syncthreads();
  for (int size = 2; size <= 4096; size <<= 1) {
    for (int stride = size >> 1; stride > 0; stride >>= 1) {
      for (int c = tid; c < 2048; c += 1024) {
        int i = 2*c - (c & (stride - 1));
        int j = i + stride;
        bool up = ((i & size) == 0);
        float a = srt[i], bb = srt[j];
        if ((a > bb) == up) { srt[i] = bb; srt[j] = a; }
      }
      __syncthreads();
    }
  }
  float scale = fmaxf(srt[2047], 1e-6f);   // lower median of 4096
  bool pos = srt[4095] > 0.f;
#pragma unroll
  for (int u = 0; u < 4; ++u) {
    int j = tid + u*1024;
    int b = j >> 11, p = j & 2047;
    float r = pos ? expf(-m[u]/scale) : 1.f;
    float* ob = out + ((size_t)(b*3 + k)*8)*2048 + p;
#pragma unroll
    for (int f = 0; f < 8; ++f) ob[f*2048] = r;
  }
}

extern "C" void kernel_launch(void* const* d_in, const int* in_sizes, int n_in,
                              void* d_out, int out_size, void* d_ws, size_t ws_size,
                              hipStream_t stream) {
  (void)in_sizes; (void)n_in; (void)out_size; (void)ws_size;
  const float4* pts = (const float4*)d_in[0];
  float* ws = (float*)d_ws;
  float4* bq   = (float4*)ws;                     // B*F*P*4   = 131072 floats
  float4* qfw  = (float4*)(ws + 131072);          // B*T*P*4   = 114688 floats
  float*  S    = ws + 131072 + 114688;            // 3*ROWS    =  86016 floats
  float4* pts2 = (float4*)(ws + 131072 + 114688 + 86016);  // B*F*P*4 = 131072 floats
  float*  out = (float*)d_out;

  hipLaunchKernelGGL(kA_bearing, dim3(B_*F_), dim3(256), 0, stream, pts, bq, pts2);
  hipLaunchKernelGGL(kB_qfwd,    dim3(ROWS/256), dim3(256), 0, stream, bq, qfw);
  hipLaunchKernelGGL(kC_select,  dim3(ROWS/4), dim3(256), 0, stream, pts2, qfw, S);
  hipLaunchKernelGGL(kE_final,   dim3(3), dim3(1024), 0, stream, S, out);
}

// Round 4
// 198.337 us; speedup vs baseline: 1.5597x; 1.1843x over previous
//
#include <hip/hip_runtime.h>
#include <math.h>

typedef unsigned long long u64;
typedef unsigned int u32;

#define B_ 2
#define F_ 8
#define P_ 2048
#define T_ 7                   // F-1
#define ROWS (B_*T_*P_)        // 28672
#define SENT_OU 0xFFFFFFFFu

// ---- keys as positive-normal doubles: bit pattern 0x4000.. | ou<<16 | idx ----
__device__ __forceinline__ double pack_key(u32 ou, u32 idx) {
  u64 bits = 0x4000000000000000ull | ((u64)ou << 16) | idx;
  return __longlong_as_double((long long)bits);
}

#define CED(arr,a,b) do { double _x=arr[a], _y=arr[b]; arr[a]=fmin(_x,_y); arr[b]=fmax(_x,_y); } while(0)

// Batcher odd-even mergesort, 8 elements, 19 comparators
__device__ __forceinline__ void sort8d(double* k) {
  CED(k,0,1); CED(k,2,3); CED(k,4,5); CED(k,6,7);
  CED(k,0,2); CED(k,1,3); CED(k,4,6); CED(k,5,7);
  CED(k,1,2); CED(k,5,6);
  CED(k,0,4); CED(k,1,5); CED(k,2,6); CED(k,3,7);
  CED(k,2,4); CED(k,3,5);
  CED(k,1,2); CED(k,3,4); CED(k,5,6);
}

// A,B sorted ascending -> A = lowest 8 of the 16, sorted
__device__ __forceinline__ void low8(double* A, const double* Bv) {
#pragma unroll
  for (int i = 0; i < 8; ++i) A[i] = fmin(A[i], Bv[7-i]);   // bitonic
#pragma unroll
  for (int st = 4; st >= 1; st >>= 1) {
#pragma unroll
    for (int i = 0; i < 8; ++i) {
      if ((i & st) == 0) { CED(A, i, i + st); }
    }
  }
}

// ---- DPP wave64 reductions (no DS pipe): shr1/2/4/8 + bcast15/31; valid in lane 63 ----
__device__ __forceinline__ u32 dpp_min_u32(u32 x) {
  u32 t;
  t = (u32)__builtin_amdgcn_update_dpp((int)x,(int)x,0x111,0xf,0xf,false); x = t<x?t:x;
  t = (u32)__builtin_amdgcn_update_dpp((int)x,(int)x,0x112,0xf,0xf,false); x = t<x?t:x;
  t = (u32)__builtin_amdgcn_update_dpp((int)x,(int)x,0x114,0xf,0xf,false); x = t<x?t:x;
  t = (u32)__builtin_amdgcn_update_dpp((int)x,(int)x,0x118,0xf,0xf,false); x = t<x?t:x;
  t = (u32)__builtin_amdgcn_update_dpp((int)x,(int)x,0x142,0xf,0xf,false); x = t<x?t:x;
  t = (u32)__builtin_amdgcn_update_dpp((int)x,(int)x,0x143,0xf,0xf,false); x = t<x?t:x;
  return x;
}
__device__ __forceinline__ float dpp_sum_f32(float x) {
  float t;
  t = __uint_as_float((u32)__builtin_amdgcn_update_dpp(0,(int)__float_as_uint(x),0x111,0xf,0xf,false)); x += t;
  t = __uint_as_float((u32)__builtin_amdgcn_update_dpp(0,(int)__float_as_uint(x),0x112,0xf,0xf,false)); x += t;
  t = __uint_as_float((u32)__builtin_amdgcn_update_dpp(0,(int)__float_as_uint(x),0x114,0xf,0xf,false)); x += t;
  t = __uint_as_float((u32)__builtin_amdgcn_update_dpp(0,(int)__float_as_uint(x),0x118,0xf,0xf,false)); x += t;
  t = __uint_as_float((u32)__builtin_amdgcn_update_dpp(0,(int)__float_as_uint(x),0x142,0xf,0xf,false)); x += t;
  t = __uint_as_float((u32)__builtin_amdgcn_update_dpp(0,(int)__float_as_uint(x),0x143,0xf,0xf,false)); x += t;
  return x;
}

// ---------------- Kernel A: bearing quaternions + |q|^2 prepack ----------------
__global__ __launch_bounds__(256) void kA_bearing(const float4* __restrict__ pts,
                                                  float4* __restrict__ bq,
                                                  float4* __restrict__ pts2) {
  int bf = blockIdx.x;                // b*F + f
  const float4* base = pts + (size_t)bf * P_;
  int tid = threadIdx.x;
  float x[8], y[8], z[8];
  float mnx =  INFINITY, mny =  INFINITY, mnz =  INFINITY;
  float mxx = -INFINITY, mxy = -INFINITY, mxz = -INFINITY;
#pragma unroll
  for (int i = 0; i < 8; ++i) {
    float4 v = base[tid + i*256];
    x[i]=v.x; y[i]=v.y; z[i]=v.z;
    mnx=fminf(mnx,v.x); mny=fminf(mny,v.y); mnz=fminf(mnz,v.z);
    mxx=fmaxf(mxx,v.x); mxy=fmaxf(mxy,v.y); mxz=fmaxf(mxz,v.z);
  }
#pragma unroll
  for (int off = 32; off >= 1; off >>= 1) {
    mnx=fminf(mnx,__shfl_xor(mnx,off)); mny=fminf(mny,__shfl_xor(mny,off)); mnz=fminf(mnz,__shfl_xor(mnz,off));
    mxx=fmaxf(mxx,__shfl_xor(mxx,off)); mxy=fmaxf(mxy,__shfl_xor(mxy,off)); mxz=fmaxf(mxz,__shfl_xor(mxz,off));
  }
  __shared__ float red[4][6];
  int wid = tid >> 6, lane = tid & 63;
  if (lane == 0) { red[wid][0]=mnx; red[wid][1]=mny; red[wid][2]=mnz;
                   red[wid][3]=mxx; red[wid][4]=mxy; red[wid][5]=mxz; }
  __syncthreads();
  mnx=fminf(fminf(red[0][0],red[1][0]),fminf(red[2][0],red[3][0]));
  mny=fminf(fminf(red[0][1],red[1][1]),fminf(red[2][1],red[3][1]));
  mnz=fminf(fminf(red[0][2],red[1][2]),fminf(red[2][2],red[3][2]));
  mxx=fmaxf(fmaxf(red[0][3],red[1][3]),fmaxf(red[2][3],red[3][3]));
  mxy=fmaxf(fmaxf(red[0][4],red[1][4]),fmaxf(red[2][4],red[3][4]));
  mxz=fmaxf(fmaxf(red[0][5],red[1][5]),fmaxf(red[2][5],red[3][5]));
  float cx=(mnx+mxx)*0.5f, cy=(mny+mxy)*0.5f, cz=(mnz+mxz)*0.5f;
#pragma unroll
  for (int i = 0; i < 8; ++i) {
    float dx=x[i]-cx, dy=y[i]-cy, dz=z[i]-cz;
    float n = sqrtf(((dx*dx) + dy*dy) + dz*dz);
    n = fmaxf(n, 1e-12f);
    float dxn = dx/n, dyn = dy/n, dzn = dz/n;
    float dotc = fminf(fmaxf(dyn, -0.99999990f), 0.99999990f);
    float half = acosf(dotc) * 0.5f;
    float an = sqrtf(dzn*dzn + dxn*dxn);
    an = fmaxf(an, 1e-12f);
    float axx = dzn/an, axz = (-dxn)/an;
    float s = sinf(half), w = cosf(half);
    bq[(size_t)bf*P_ + tid + i*256] = make_float4(w, axx*s, 0.f, axz*s);
    float qs = fmaf(x[i],x[i], fmaf(y[i],y[i], z[i]*z[i]));
    pts2[(size_t)bf*P_ + tid + i*256] = make_float4(x[i], y[i], z[i], qs);
  }
}

// ---------------- Kernel B: forward quaternions ----------------
__global__ __launch_bounds__(256) void kB_qfwd(const float4* __restrict__ bq,
                                               float4* __restrict__ qf) {
  int i = blockIdx.x*256 + threadIdx.x;   // over B*T*P
  int p = i & (P_-1);
  int t = (i >> 11) % T_;
  int b = i / (T_*P_);
  float4 s = bq[((size_t)(b*F_ + t))*P_ + p];       // frame t (src)
  float4 a = bq[((size_t)(b*F_ + t + 1))*P_ + p];   // frame t+1 (tgt)
  float aw=a.x, ax=a.y, ay=a.z, az=a.w;
  float bw=s.x, bx=-s.y, by=-s.z, bz=-s.w;          // conj
  float w  = ((aw*bw - ax*bx) - ay*by) - az*bz;
  float xo = ((aw*bx + ax*bw) + ay*bz) - az*by;
  float yo = ((aw*by - ax*bz) + ay*bw) + az*bx;
  float zo = ((aw*bz + ax*by) - ay*bx) + az*bw;
  float n = sqrtf(((w*w + xo*xo) + yo*yo) + zo*zo);
  n = fmaxf(n, 1e-12f);
  qf[i] = make_float4(w/n, xo/n, yo/n, zo/n);
}

// ---------------- Kernel C: top-40 selection + geo sums, 2 rows/wave ----------------
__device__ __forceinline__ double makekey1(const float4* __restrict__ pbase, int q,
                                           float px, float py, float pz, float ps) {
  float4 c = pbase[q];
  float dot = fmaf(px, c.x, fmaf(py, c.y, pz*c.z));
  float v = (2.f*dot - ps) - c.w;
  float nd = -v;
  u32 u = __float_as_uint(nd);
  u32 ou = (u & 0x80000000u) ? ~u : (u | 0x80000000u);
  return pack_key(ou, (u32)q);
}

__device__ __forceinline__ void makekey2(float4 c, int q,
                                         float px0,float py0,float pz0,float ps0,
                                         float px1,float py1,float pz1,float ps1,
                                         double& k0, double& k1) {
  float dot0 = fmaf(px0, c.x, fmaf(py0, c.y, pz0*c.z));
  float v0 = (2.f*dot0 - ps0) - c.w;
  float nd0 = -v0;
  u32 u0 = __float_as_uint(nd0);
  u32 ou0 = (u0 & 0x80000000u) ? ~u0 : (u0 | 0x80000000u);
  k0 = pack_key(ou0, (u32)q);
  float dot1 = fmaf(px1, c.x, fmaf(py1, c.y, pz1*c.z));
  float v1 = (2.f*dot1 - ps1) - c.w;
  float nd1 = -v1;
  u32 u1 = __float_as_uint(nd1);
  u32 ou1 = (u1 & 0x80000000u) ? ~u1 : (u1 | 0x80000000u);
  k1 = pack_key(ou1, (u32)q);
}

__global__ __launch_bounds__(64) void kC_select(const float4* __restrict__ pts2,
                                                const float4* __restrict__ qf,
                                                float* __restrict__ S) {
  int lane = threadIdx.x;              // 64-thread blocks, 1 wave, 2 rows
  int row0 = blockIdx.x*2;
  int row1 = row0 + 1;
  int p0 = row0 & (P_-1);
  int bt = row0 >> 11;                 // same tile for both rows (p0 even)
  int t  = bt % T_;
  int b  = bt / T_;
  const float4* pbase = pts2 + (size_t)(b*F_ + t) * P_;
  float4 pw0 = pbase[p0];
  float4 pw1 = pbase[p0+1];
  float px0=pw0.x, py0=pw0.y, pz0=pw0.z, ps0=pw0.w;
  float px1=pw1.x, py1=pw1.y, pz1=pw1.z, ps1=pw1.w;

  double A0[8],A1[8],B0[8],B1[8],C0[8],C1[8];
#pragma unroll
  for (int s = 0; s < 8; ++s) { float4 c = pbase[s*64+lane];
    makekey2(c, s*64+lane, px0,py0,pz0,ps0, px1,py1,pz1,ps1, A0[s], A1[s]); }
  sort8d(A0); sort8d(A1);
#pragma unroll
  for (int s = 0; s < 8; ++s) { float4 c = pbase[(8+s)*64+lane];
    makekey2(c, (8+s)*64+lane, px0,py0,pz0,ps0, px1,py1,pz1,ps1, B0[s], B1[s]); }
  sort8d(B0); sort8d(B1);
  low8(A0, B0); low8(A1, B1);
#pragma unroll
  for (int s = 0; s < 8; ++s) { float4 c = pbase[(16+s)*64+lane];
    makekey2(c, (16+s)*64+lane, px0,py0,pz0,ps0, px1,py1,pz1,ps1, B0[s], B1[s]); }
  sort8d(B0); sort8d(B1);
#pragma unroll
  for (int s = 0; s < 8; ++s) { float4 c = pbase[(24+s)*64+lane];
    makekey2(c, (24+s)*64+lane, px0,py0,pz0,ps0, px1,py1,pz1,ps1, C0[s], C1[s]); }
  sort8d(C0); sort8d(C1);
  low8(B0, C0); low8(B1, C1);
  low8(A0, B0); low8(A1, B1);          // A = lane-local sorted top-8 of 32

  u32 OU0[8], IX0[8], OU1[8], IX1[8];
#pragma unroll
  for (int j = 0; j < 8; ++j) {
    u64 b0 = (u64)__double_as_longlong(A0[j]);
    OU0[j] = (u32)(b0 >> 16); IX0[j] = (u32)(b0 & 0xffffu);
    u64 b1 = (u64)__double_as_longlong(A1[j]);
    OU1[j] = (u32)(b1 >> 16); IX1[j] = (u32)(b1 & 0xffffu);
  }

  u32 last_ou0=0, last_ix0=0, cap0=0;
  u32 last_ou1=0, last_ix1=0, cap1=0;

#pragma unroll 1
  for (int i = 0; i < 40; ++i) {
    // ---- row 0 ----
    if (__any(OU0[0] == SENT_OU)) {    // exact refill, ~never taken
      bool need = (OU0[0] == SENT_OU);
      double lastK = pack_key(last_ou0, last_ix0);
      double best = __builtin_huge_val();
#pragma unroll
      for (int s2 = 0; s2 < 32; ++s2) {
        double kk = makekey1(pbase, s2*64 + lane, px0,py0,pz0,ps0);
        best = (kk > lastK && kk < best) ? kk : best;
      }
      if (need && best < __builtin_huge_val()) {
        u64 bb = (u64)__double_as_longlong(best);
        OU0[0] = (u32)(bb >> 16); IX0[0] = (u32)(bb & 0xffffu);
      }
    }
    u32 m0 = dpp_min_u32(OU0[0]);
    u32 smin0 = (u32)__builtin_amdgcn_readlane((int)m0, 63);
    u64 bal0 = __ballot(OU0[0] == smin0);
    u32 sidx0; bool iam0;
    if (__popcll(bal0) == 1) {
      int wl = (int)__builtin_ctzll(bal0);
      sidx0 = (u32)__builtin_amdgcn_readlane((int)IX0[0], wl);
      iam0 = (lane == wl);
    } else {                            // exact tie-break on idx (rare, uniform)
      u32 tt = (OU0[0] == smin0) ? IX0[0] : 0xFFFFFFFFu;
      sidx0 = (u32)__builtin_amdgcn_readlane((int)dpp_min_u32(tt), 63);
      iam0 = (OU0[0] == smin0) && (IX0[0] == sidx0);
    }
    cap0 = (lane == i) ? sidx0 : cap0;
    last_ou0 = iam0 ? smin0 : last_ou0;
    last_ix0 = iam0 ? sidx0 : last_ix0;
#pragma unroll
    for (int j = 0; j < 7; ++j) {
      OU0[j] = iam0 ? OU0[j+1] : OU0[j];
      IX0[j] = iam0 ? IX0[j+1] : IX0[j];
    }
    OU0[7] = iam0 ? SENT_OU : OU0[7];

    // ---- row 1 ----
    if (__any(OU1[0] == SENT_OU)) {
      bool need = (OU1[0] == SENT_OU);
      double lastK = pack_key(last_ou1, last_ix1);
      double best = __builtin_huge_val();
#pragma unroll
      for (int s2 = 0; s2 < 32; ++s2) {
        double kk = makekey1(pbase, s2*64 + lane, px1,py1,pz1,ps1);
        best = (kk > lastK && kk < best) ? kk : best;
      }
      if (need && best < __builtin_huge_val()) {
        u64 bb = (u64)__double_as_longlong(best);
        OU1[0] = (u32)(bb >> 16); IX1[0] = (u32)(bb & 0xffffu);
      }
    }
    u32 m1 = dpp_min_u32(OU1[0]);
    u32 smin1 = (u32)__builtin_amdgcn_readlane((int)m1, 63);
    u64 bal1 = __ballot(OU1[0] == smin1);
    u32 sidx1; bool iam1;
    if (__popcll(bal1) == 1) {
      int wl = (int)__builtin_ctzll(bal1);
      sidx1 = (u32)__builtin_amdgcn_readlane((int)IX1[0], wl);
      iam1 = (lane == wl);
    } else {
      u32 tt = (OU1[0] == smin1) ? IX1[0] : 0xFFFFFFFFu;
      sidx1 = (u32)__builtin_amdgcn_readlane((int)dpp_min_u32(tt), 63);
      iam1 = (OU1[0] == smin1) && (IX1[0] == sidx1);
    }
    cap1 = (lane == i) ? sidx1 : cap1;
    last_ou1 = iam1 ? smin1 : last_ou1;
    last_ix1 = iam1 ? sidx1 : last_ix1;
#pragma unroll
    for (int j = 0; j < 7; ++j) {
      OU1[j] = iam1 ? OU1[j+1] : OU1[j];
      IX1[j] = iam1 ? IX1[j+1] : IX1[j];
    }
    OU1[7] = iam1 ? SENT_OU : OU1[7];
  }

  // ---- epilogue: geodesic sums for both rows (interleaved ILP) ----
  const float4* qbt = qf + (size_t)bt * P_;
  float4 qp0 = qf[row0];
  float4 qp1 = qf[row1];
  float geo0 = 0.f, geo1 = 0.f;
  if (lane < 40) {
    float4 n0 = qbt[cap0];
    float d0 = ((qp0.x*n0.x + qp0.y*n0.y) + qp0.z*n0.z) + qp0.w*n0.w;
    geo0 = 2.f * acosf(fminf(fabsf(d0), 0.99999990f));
    float4 n1 = qbt[cap1];
    float d1 = ((qp1.x*n1.x + qp1.y*n1.y) + qp1.z*n1.z) + qp1.w*n1.w;
    geo1 = 2.f * acosf(fminf(fabsf(d1), 0.99999990f));
  }
  float g40_0 = dpp_sum_f32(geo0);
  float g15_0 = dpp_sum_f32((lane < 15) ? geo0 : 0.f);
  float g5_0  = dpp_sum_f32((lane < 5)  ? geo0 : 0.f);
  float g40_1 = dpp_sum_f32(geo1);
  float g15_1 = dpp_sum_f32((lane < 15) ? geo1 : 0.f);
  float g5_1  = dpp_sum_f32((lane < 5)  ? geo1 : 0.f);
  if (lane == 63) {
    S[0*ROWS + row0] = g5_0  / 5.f;
    S[1*ROWS + row0] = g15_0 / 15.f;
    S[2*ROWS + row0] = g40_0 / 40.f;
    S[0*ROWS + row1] = g5_1  / 5.f;
    S[1*ROWS + row1] = g15_1 / 15.f;
    S[2*ROWS + row1] = g40_1 / 40.f;
  }
}

// ---------------- Kernel E: mean over t, median, output ----------------
__global__ __launch_bounds__(1024) void kE_final(const float* __restrict__ S,
                                                 float* __restrict__ out) {
  int k = blockIdx.x;                  // scale index 0..2
  int tid = threadIdx.x;
  __shared__ float srt[4096];
  const float* Sk = S + (size_t)k * ROWS;
  float m[4];
#pragma unroll
  for (int u = 0; u < 4; ++u) {
    int j = tid + u*1024;              // j = b*2048 + p
    int b = j >> 11, p = j & 2047;
    float acc = 0.f;
#pragma unroll
    for (int t = 0; t < 7; ++t) acc += Sk[(b*7 + t)*2048 + p];
    m[u] = acc / 7.f;
    srt[j] = m[u];
  }
  __syncthreads();
  for (int size = 2; size <= 4096; size <<= 1) {
    for (int stride = size >> 1; stride > 0; stride >>= 1) {
      for (int c = tid; c < 2048; c += 1024) {
        int i = 2*c - (c & (stride - 1));
        int j = i + stride;
        bool up = ((i & size) == 0);
        float a = srt[i], bb = srt[j];
        if ((a > bb) == up) { srt[i] = bb; srt[j] = a; }
      }
      __syncthreads();
    }
  }
  float scale = fmaxf(srt[2047], 1e-6f);   // lower median of 4096
  bool pos = srt[4095] > 0.f;
#pragma unroll
  for (int u = 0; u < 4; ++u) {
    int j = tid + u*1024;
    int b = j >> 11, p = j & 2047;
    float r = pos ? expf(-m[u]/scale) : 1.f;
    float* ob = out + ((size_t)(b*3 + k)*8)*2048 + p;
#pragma unroll
    for (int f = 0; f < 8; ++f) ob[f*2048] = r;
  }
}

extern "C" void kernel_launch(void* const* d_in, const int* in_sizes, int n_in,
                              void* d_out, int out_size, void* d_ws, size_t ws_size,
                              hipStream_t stream) {
  (void)in_sizes; (void)n_in; (void)out_size; (void)ws_size;
  const float4* pts = (const float4*)d_in[0];
  float* ws = (float*)d_ws;
  float4* bq   = (float4*)ws;                     // B*F*P*4   = 131072 floats
  float4* qfw  = (float4*)(ws + 131072);          // B*T*P*4   = 114688 floats
  float*  S    = ws + 131072 + 114688;            // 3*ROWS    =  86016 floats
  float4* pts2 = (float4*)(ws + 131072 + 114688 + 86016);  // B*F*P*4 = 131072 floats
  float*  out = (float*)d_out;

  hipLaunchKernelGGL(kA_bearing, dim3(B_*F_), dim3(256), 0, stream, pts, bq, pts2);
  hipLaunchKernelGGL(kB_qfwd,    dim3(ROWS/256), dim3(256), 0, stream, bq, qfw);
  hipLaunchKernelGGL(kC_select,  dim3(ROWS/2), dim3(64), 0, stream, pts2, qfw, S);
  hipLaunchKernelGGL(kE_final,   dim3(3), dim3(1024), 0, stream, S, out);
}

// Round 5
// 151.725 us; speedup vs baseline: 2.0388x; 1.3072x over previous
//
#include <hip/hip_runtime.h>
#include <math.h>

typedef unsigned long long u64;
typedef unsigned int u32;

#define B_ 2
#define F_ 8
#define P_ 2048
#define T_ 7                   // F-1
#define ROWS (B_*T_*P_)        // 28672
#define SENT_OU 0xFFFFFFFFu

// ---- keys as positive-normal doubles: bit pattern 0x4000.. | ou<<16 | idx ----
// positive doubles: IEEE ordering == integer ordering -> CE = v_min_f64+v_max_f64
#define CED(arr,a,b) do { double _x=arr[a], _y=arr[b]; arr[a]=fmin(_x,_y); arr[b]=fmax(_x,_y); } while(0)

// Batcher odd-even mergesort, 8 elements, 19 comparators
__device__ __forceinline__ void sort8d(double* k) {
  CED(k,0,1); CED(k,2,3); CED(k,4,5); CED(k,6,7);
  CED(k,0,2); CED(k,1,3); CED(k,4,6); CED(k,5,7);
  CED(k,1,2); CED(k,5,6);
  CED(k,0,4); CED(k,1,5); CED(k,2,6); CED(k,3,7);
  CED(k,2,4); CED(k,3,5);
  CED(k,1,2); CED(k,3,4); CED(k,5,6);
}

// A,B sorted ascending -> A = lowest 8 of the 16, sorted
__device__ __forceinline__ void low8(double* A, const double* Bv) {
#pragma unroll
  for (int i = 0; i < 8; ++i) A[i] = fmin(A[i], Bv[7-i]);   // bitonic
#pragma unroll
  for (int st = 4; st >= 1; st >>= 1) {
#pragma unroll
    for (int i = 0; i < 8; ++i) {
      if ((i & st) == 0) { CED(A, i, i + st); }
    }
  }
}

// ---- quarter(16-lane)-local butterfly reductions via DPP: result in ALL lanes ----
// steps: quad_perm xor1 (0xB1), quad_perm xor2 (0x4E), row_half_mirror (0x141),
// row_mirror (0x140). Each combines lane with a disjoint coset -> full 16-min.
__device__ __forceinline__ u32 bfly16_min_u32(u32 x) {
  u32 t;
  t = (u32)__builtin_amdgcn_update_dpp((int)x,(int)x,0x0B1,0xF,0xF,false); x = t<x?t:x;
  t = (u32)__builtin_amdgcn_update_dpp((int)x,(int)x,0x04E,0xF,0xF,false); x = t<x?t:x;
  t = (u32)__builtin_amdgcn_update_dpp((int)x,(int)x,0x141,0xF,0xF,false); x = t<x?t:x;
  t = (u32)__builtin_amdgcn_update_dpp((int)x,(int)x,0x140,0xF,0xF,false); x = t<x?t:x;
  return x;
}
__device__ __forceinline__ float bfly16_sum_f32(float x) {
  float t;
  t = __uint_as_float((u32)__builtin_amdgcn_update_dpp((int)__float_as_uint(x),(int)__float_as_uint(x),0x0B1,0xF,0xF,false)); x += t;
  t = __uint_as_float((u32)__builtin_amdgcn_update_dpp((int)__float_as_uint(x),(int)__float_as_uint(x),0x04E,0xF,0xF,false)); x += t;
  t = __uint_as_float((u32)__builtin_amdgcn_update_dpp((int)__float_as_uint(x),(int)__float_as_uint(x),0x141,0xF,0xF,false)); x += t;
  t = __uint_as_float((u32)__builtin_amdgcn_update_dpp((int)__float_as_uint(x),(int)__float_as_uint(x),0x140,0xF,0xF,false)); x += t;
  return x;
}

// ---------------- Kernel A: bearing quaternions + |q|^2 prepack ----------------
__global__ __launch_bounds__(256) void kA_bearing(const float4* __restrict__ pts,
                                                  float4* __restrict__ bq,
                                                  float4* __restrict__ pts2) {
  int bf = blockIdx.x;                // b*F + f
  const float4* base = pts + (size_t)bf * P_;
  int tid = threadIdx.x;
  float x[8], y[8], z[8];
  float mnx =  INFINITY, mny =  INFINITY, mnz =  INFINITY;
  float mxx = -INFINITY, mxy = -INFINITY, mxz = -INFINITY;
#pragma unroll
  for (int i = 0; i < 8; ++i) {
    float4 v = base[tid + i*256];
    x[i]=v.x; y[i]=v.y; z[i]=v.z;
    mnx=fminf(mnx,v.x); mny=fminf(mny,v.y); mnz=fminf(mnz,v.z);
    mxx=fmaxf(mxx,v.x); mxy=fmaxf(mxy,v.y); mxz=fmaxf(mxz,v.z);
  }
#pragma unroll
  for (int off = 32; off >= 1; off >>= 1) {
    mnx=fminf(mnx,__shfl_xor(mnx,off)); mny=fminf(mny,__shfl_xor(mny,off)); mnz=fminf(mnz,__shfl_xor(mnz,off));
    mxx=fmaxf(mxx,__shfl_xor(mxx,off)); mxy=fmaxf(mxy,__shfl_xor(mxy,off)); mxz=fmaxf(mxz,__shfl_xor(mxz,off));
  }
  __shared__ float red[4][6];
  int wid = tid >> 6, lane = tid & 63;
  if (lane == 0) { red[wid][0]=mnx; red[wid][1]=mny; red[wid][2]=mnz;
                   red[wid][3]=mxx; red[wid][4]=mxy; red[wid][5]=mxz; }
  __syncthreads();
  mnx=fminf(fminf(red[0][0],red[1][0]),fminf(red[2][0],red[3][0]));
  mny=fminf(fminf(red[0][1],red[1][1]),fminf(red[2][1],red[3][1]));
  mnz=fminf(fminf(red[0][2],red[1][2]),fminf(red[2][2],red[3][2]));
  mxx=fmaxf(fmaxf(red[0][3],red[1][3]),fmaxf(red[2][3],red[3][3]));
  mxy=fmaxf(fmaxf(red[0][4],red[1][4]),fmaxf(red[2][4],red[3][4]));
  mxz=fmaxf(fmaxf(red[0][5],red[1][5]),fmaxf(red[2][5],red[3][5]));
  float cx=(mnx+mxx)*0.5f, cy=(mny+mxy)*0.5f, cz=(mnz+mxz)*0.5f;
#pragma unroll
  for (int i = 0; i < 8; ++i) {
    float dx=x[i]-cx, dy=y[i]-cy, dz=z[i]-cz;
    float n = sqrtf(((dx*dx) + dy*dy) + dz*dz);
    n = fmaxf(n, 1e-12f);
    float dxn = dx/n, dyn = dy/n, dzn = dz/n;
    float dotc = fminf(fmaxf(dyn, -0.99999990f), 0.99999990f);
    float half = acosf(dotc) * 0.5f;
    float an = sqrtf(dzn*dzn + dxn*dxn);
    an = fmaxf(an, 1e-12f);
    float axx = dzn/an, axz = (-dxn)/an;
    float s = sinf(half), w = cosf(half);
    bq[(size_t)bf*P_ + tid + i*256] = make_float4(w, axx*s, 0.f, axz*s);
    float qs = fmaf(x[i],x[i], fmaf(y[i],y[i], z[i]*z[i]));
    pts2[(size_t)bf*P_ + tid + i*256] = make_float4(x[i], y[i], z[i], qs);
  }
}

// ---------------- Kernel B: forward quaternions ----------------
__global__ __launch_bounds__(256) void kB_qfwd(const float4* __restrict__ bq,
                                               float4* __restrict__ qf) {
  int i = blockIdx.x*256 + threadIdx.x;   // over B*T*P
  int p = i & (P_-1);
  int t = (i >> 11) % T_;
  int b = i / (T_*P_);
  float4 s = bq[((size_t)(b*F_ + t))*P_ + p];       // frame t (src)
  float4 a = bq[((size_t)(b*F_ + t + 1))*P_ + p];   // frame t+1 (tgt)
  float aw=a.x, ax=a.y, ay=a.z, az=a.w;
  float bw=s.x, bx=-s.y, by=-s.z, bz=-s.w;          // conj
  float w  = ((aw*bw - ax*bx) - ay*by) - az*bz;
  float xo = ((aw*bx + ax*bw) + ay*bz) - az*by;
  float yo = ((aw*by - ax*bz) + ay*bw) + az*bx;
  float zo = ((aw*bz + ax*by) - ay*bx) + az*bw;
  float n = sqrtf(((w*w + xo*xo) + yo*yo) + zo*zo);
  n = fmaxf(n, 1e-12f);
  qf[i] = make_float4(w/n, xo/n, yo/n, zo/n);
}

// ---------------- Kernel C: top-40, quarter-wave rows (8 rows/wave) ----------------
__device__ __forceinline__ double mkkey(float4 c, u32 q,
                                        float px, float py, float pz, float ps) {
  float dot = fmaf(px, c.x, fmaf(py, c.y, pz*c.z));
  float v = (2.f*dot - ps) - c.w;      // = reference neg_dist
  float nd = -v;                       // ascending distance
  u32 u = __float_as_uint(nd);
  u32 ou = (u & 0x80000000u) ? ~u : (u | 0x80000000u);
  return __longlong_as_double((long long)(0x4000000000000000ull | ((u64)ou << 16) | q));
}

// one pop of the 4-rows-per-chain stream (each 16-lane quarter owns a row)
__device__ __forceinline__ void popstep(u32 (&OU)[8], u32 (&IX)[8],
                                        u32& LOU, u32& LIX, u32& CAP, int imod,
                                        int slot, const float4* __restrict__ pbase,
                                        float px, float py, float pz, float ps) {
  if (__any(OU[0] == SENT_OU)) {       // exact refill, cold (P ~ 0.1%/lane-row)
    bool need = (OU[0] == SENT_OU);
    u64 lastK = ((u64)LOU << 16) | LIX;
    u64 best = ~0ull;
    for (int j = 0; j < 128; ++j) {
      u32 q = (u32)(j*16 + slot);
      float4 c = pbase[q];
      float dot = fmaf(px, c.x, fmaf(py, c.y, pz*c.z));
      float v = (2.f*dot - ps) - c.w;
      u32 u = __float_as_uint(-v);
      u32 ou = (u & 0x80000000u) ? ~u : (u | 0x80000000u);
      u64 kk = ((u64)ou << 16) | q;
      if (kk > lastK && kk < best) best = kk;
    }
    if (need && best != ~0ull) { OU[0] = (u32)(best >> 16); IX[0] = (u32)(best & 0xffffu); }
  }
  u32 qmin = bfly16_min_u32(OU[0]);                  // all lanes get quarter min ou
  bool meq = (OU[0] == qmin);
  u32 tt   = meq ? IX[0] : 0xFFFFFFFFu;
  u32 widx = bfly16_min_u32(tt);                     // exact idx tie-break, all lanes
  bool iam = meq && (IX[0] == widx);
  CAP = (slot == imod) ? widx : CAP;
  LOU = iam ? qmin : LOU;
  LIX = iam ? widx : LIX;
#pragma unroll
  for (int jj = 0; jj < 7; ++jj) {
    OU[jj] = iam ? OU[jj+1] : OU[jj];
    IX[jj] = iam ? IX[jj+1] : IX[jj];
  }
  OU[7] = iam ? SENT_OU : OU[7];
}

__global__ __launch_bounds__(64) void kC_select(const float4* __restrict__ pts2,
                                                const float4* __restrict__ qf,
                                                float* __restrict__ S) {
  int lane = threadIdx.x;
  int slot = lane & 15;                // position within 16-lane quarter
  int quarter = lane >> 4;             // 0..3
  int p0 = (blockIdx.x * 8) & (P_-1);  // 8 consecutive rows, same tile
  int bt = (blockIdx.x * 8) >> 11;     // b*7 + t
  int t  = bt % T_;
  int b  = bt / T_;
  const float4* pbase = pts2 + (size_t)(b*F_ + t) * P_;

  int prowA = p0 + quarter;            // chain A row for my quarter
  int prowB = p0 + 4 + quarter;        // chain B row
  float4 pwA = pbase[prowA];
  float4 pwB = pbase[prowB];
  float pxA=pwA.x, pyA=pwA.y, pzA=pwA.z, psA=pwA.w;
  float pxB=pwB.x, pyB=pwB.y, pzB=pwB.z, psB=pwB.w;

  // ---- sort phase: per lane 128 candidates (j*16+slot), keep top-8 per chain ----
  double accA[8], accB[8];
#pragma unroll
  for (int j = 0; j < 8; ++j) { accA[j] = __builtin_huge_val(); accB[j] = __builtin_huge_val(); }
#pragma unroll 2
  for (int batch = 0; batch < 16; ++batch) {
    int qb = batch*128 + slot;
    float4 c[8];
#pragma unroll
    for (int u = 0; u < 8; ++u) c[u] = pbase[qb + u*16];
    double kA[8], kB[8];
#pragma unroll
    for (int u = 0; u < 8; ++u) kA[u] = mkkey(c[u], (u32)(qb + u*16), pxA,pyA,pzA,psA);
    sort8d(kA);
    low8(accA, kA);
#pragma unroll
    for (int u = 0; u < 8; ++u) kB[u] = mkkey(c[u], (u32)(qb + u*16), pxB,pyB,pzB,psB);
    sort8d(kB);
    low8(accB, kB);
  }

  // unpack into register queues
  u32 OUA[8], IXA[8], OUB[8], IXB[8];
#pragma unroll
  for (int j = 0; j < 8; ++j) {
    u64 ba = (u64)__double_as_longlong(accA[j]);
    OUA[j] = (u32)(ba >> 16); IXA[j] = (u32)(ba & 0xffffu);
    u64 bb = (u64)__double_as_longlong(accB[j]);
    OUB[j] = (u32)(bb >> 16); IXB[j] = (u32)(bb & 0xffffu);
  }

  u32 louA=0, lixA=0, capA1=0, capA2=0, capA3=0;
  u32 louB=0, lixB=0, capB1=0, capB2=0, capB3=0;

#pragma unroll 1
  for (int i = 0; i < 16; ++i) {       // winners 0..15 -> cap1[slot==i]
    popstep(OUA, IXA, louA, lixA, capA1, i, slot, pbase, pxA,pyA,pzA,psA);
    popstep(OUB, IXB, louB, lixB, capB1, i, slot, pbase, pxB,pyB,pzB,psB);
  }
#pragma unroll 1
  for (int i = 0; i < 16; ++i) {       // winners 16..31 -> cap2
    popstep(OUA, IXA, louA, lixA, capA2, i, slot, pbase, pxA,pyA,pzA,psA);
    popstep(OUB, IXB, louB, lixB, capB2, i, slot, pbase, pxB,pyB,pzB,psB);
  }
#pragma unroll 1
  for (int i = 0; i < 8; ++i) {        // winners 32..39 -> cap3 (slots 0..7)
    popstep(OUA, IXA, louA, lixA, capA3, i, slot, pbase, pxA,pyA,pzA,psA);
    popstep(OUB, IXB, louB, lixB, capB3, i, slot, pbase, pxB,pyB,pzB,psB);
  }

  // ---- epilogue: geodesic sums per row ----
  int rowA = bt*P_ + prowA;
  int rowB = bt*P_ + prowB;
  const float4* qbt = qf + (size_t)bt * P_;
  float4 qpA = qf[rowA];
  float4 qpB = qf[rowB];

  float4 n; float d;
  n = qbt[capA1]; d = ((qpA.x*n.x + qpA.y*n.y) + qpA.z*n.z) + qpA.w*n.w;
  float gA1 = 2.f * acosf(fminf(fabsf(d), 0.99999990f));
  n = qbt[capA2]; d = ((qpA.x*n.x + qpA.y*n.y) + qpA.z*n.z) + qpA.w*n.w;
  float gA2 = 2.f * acosf(fminf(fabsf(d), 0.99999990f));
  n = qbt[capA3]; d = ((qpA.x*n.x + qpA.y*n.y) + qpA.z*n.z) + qpA.w*n.w;
  float gA3 = (slot < 8) ? 2.f * acosf(fminf(fabsf(d), 0.99999990f)) : 0.f;
  n = qbt[capB1]; d = ((qpB.x*n.x + qpB.y*n.y) + qpB.z*n.z) + qpB.w*n.w;
  float gB1 = 2.f * acosf(fminf(fabsf(d), 0.99999990f));
  n = qbt[capB2]; d = ((qpB.x*n.x + qpB.y*n.y) + qpB.z*n.z) + qpB.w*n.w;
  float gB2 = 2.f * acosf(fminf(fabsf(d), 0.99999990f));
  n = qbt[capB3]; d = ((qpB.x*n.x + qpB.y*n.y) + qpB.z*n.z) + qpB.w*n.w;
  float gB3 = (slot < 8) ? 2.f * acosf(fminf(fabsf(d), 0.99999990f)) : 0.f;

  float s40A = bfly16_sum_f32(gA1 + gA2 + gA3);
  float s15A = bfly16_sum_f32((slot < 15) ? gA1 : 0.f);
  float s5A  = bfly16_sum_f32((slot < 5)  ? gA1 : 0.f);
  float s40B = bfly16_sum_f32(gB1 + gB2 + gB3);
  float s15B = bfly16_sum_f32((slot < 15) ? gB1 : 0.f);
  float s5B  = bfly16_sum_f32((slot < 5)  ? gB1 : 0.f);

  if (slot == 0) {
    S[0*ROWS + rowA] = s5A  / 5.f;
    S[1*ROWS + rowA] = s15A / 15.f;
    S[2*ROWS + rowA] = s40A / 40.f;
    S[0*ROWS + rowB] = s5B  / 5.f;
    S[1*ROWS + rowB] = s15B / 15.f;
    S[2*ROWS + rowB] = s40B / 40.f;
  }
}

// ---------------- Kernel E: mean over t, median, output ----------------
__global__ __launch_bounds__(1024) void kE_final(const float* __restrict__ S,
                                                 float* __restrict__ out) {
  int k = blockIdx.x;                  // scale index 0..2
  int tid = threadIdx.x;
  __shared__ float srt[4096];
  const float* Sk = S + (size_t)k * ROWS;
  float m[4];
#pragma unroll
  for (int u = 0; u < 4; ++u) {
    int j = tid + u*1024;              // j = b*2048 + p
    int b = j >> 11, p = j & 2047;
    float acc = 0.f;
#pragma unroll
    for (int t = 0; t < 7; ++t) acc += Sk[(b*7 + t)*2048 + p];
    m[u] = acc / 7.f;
    srt[j] = m[u];
  }
  __syncthreads();
  for (int size = 2; size <= 4096; size <<= 1) {
    for (int stride = size >> 1; stride > 0; stride >>= 1) {
      for (int c = tid; c < 2048; c += 1024) {
        int i = 2*c - (c & (stride - 1));
        int j = i + stride;
        bool up = ((i & size) == 0);
        float a = srt[i], bb = srt[j];
        if ((a > bb) == up) { srt[i] = bb; srt[j] = a; }
      }
      __syncthreads();
    }
  }
  float scale = fmaxf(srt[2047], 1e-6f);   // lower median of 4096
  bool pos = srt[4095] > 0.f;
#pragma unroll
  for (int u = 0; u < 4; ++u) {
    int j = tid + u*1024;
    int b = j >> 11, p = j & 2047;
    float r = pos ? expf(-m[u]/scale) : 1.f;
    float* ob = out + ((size_t)(b*3 + k)*8)*2048 + p;
#pragma unroll
    for (int f = 0; f < 8; ++f) ob[f*2048] = r;
  }
}

extern "C" void kernel_launch(void* const* d_in, const int* in_sizes, int n_in,
                              void* d_out, int out_size, void* d_ws, size_t ws_size,
                              hipStream_t stream) {
  (void)in_sizes; (void)n_in; (void)out_size; (void)ws_size;
  const float4* pts = (const float4*)d_in[0];
  float* ws = (float*)d_ws;
  float4* bq   = (float4*)ws;                     // B*F*P*4   = 131072 floats
  float4* qfw  = (float4*)(ws + 131072);          // B*T*P*4   = 114688 floats
  float*  S    = ws + 131072 + 114688;            // 3*ROWS    =  86016 floats
  float4* pts2 = (float4*)(ws + 131072 + 114688 + 86016);  // B*F*P*4 = 131072 floats
  float*  out = (float*)d_out;

  hipLaunchKernelGGL(kA_bearing, dim3(B_*F_), dim3(256), 0, stream, pts, bq, pts2);
  hipLaunchKernelGGL(kB_qfwd,    dim3(ROWS/256), dim3(256), 0, stream, bq, qfw);
  hipLaunchKernelGGL(kC_select,  dim3(ROWS/8), dim3(64), 0, stream, pts2, qfw, S);
  hipLaunchKernelGGL(kE_final,   dim3(3), dim3(1024), 0, stream, S, out);
}

// Round 6
// 143.400 us; speedup vs baseline: 2.1572x; 1.0581x over previous
//
#include <hip/hip_runtime.h>
#include <math.h>

typedef unsigned long long u64;
typedef unsigned int u32;

#define B_ 2
#define F_ 8
#define P_ 2048
#define T_ 7                   // F-1
#define ROWS (B_*T_*P_)        // 28672
#define SENT_OU 0xFFFFFFFFu

// ---- keys as positive-normal doubles: bit pattern 0x4000.. | ou<<16 | idx ----
// positive doubles: IEEE ordering == integer ordering -> CE = v_min_f64+v_max_f64
#define CED(arr,a,b) do { double _x=arr[a], _y=arr[b]; arr[a]=fmin(_x,_y); arr[b]=fmax(_x,_y); } while(0)

// Batcher odd-even mergesort, 8 elements, 19 comparators
__device__ __forceinline__ void sort8d(double* k) {
  CED(k,0,1); CED(k,2,3); CED(k,4,5); CED(k,6,7);
  CED(k,0,2); CED(k,1,3); CED(k,4,6); CED(k,5,7);
  CED(k,1,2); CED(k,5,6);
  CED(k,0,4); CED(k,1,5); CED(k,2,6); CED(k,3,7);
  CED(k,2,4); CED(k,3,5);
  CED(k,1,2); CED(k,3,4); CED(k,5,6);
}

// A,B sorted ascending -> A = lowest 8 of the 16, sorted
__device__ __forceinline__ void low8(double* A, const double* Bv) {
#pragma unroll
  for (int i = 0; i < 8; ++i) A[i] = fmin(A[i], Bv[7-i]);   // bitonic
#pragma unroll
  for (int st = 4; st >= 1; st >>= 1) {
#pragma unroll
    for (int i = 0; i < 8; ++i) {
      if ((i & st) == 0) { CED(A, i, i + st); }
    }
  }
}

// ---- quarter(16-lane)-local butterfly reductions via DPP: result in ALL lanes ----
__device__ __forceinline__ u32 bfly16_min_u32(u32 x) {
  u32 t;
  t = (u32)__builtin_amdgcn_update_dpp((int)x,(int)x,0x0B1,0xF,0xF,false); x = t<x?t:x;
  t = (u32)__builtin_amdgcn_update_dpp((int)x,(int)x,0x04E,0xF,0xF,false); x = t<x?t:x;
  t = (u32)__builtin_amdgcn_update_dpp((int)x,(int)x,0x141,0xF,0xF,false); x = t<x?t:x;
  t = (u32)__builtin_amdgcn_update_dpp((int)x,(int)x,0x140,0xF,0xF,false); x = t<x?t:x;
  return x;
}
__device__ __forceinline__ float bfly16_sum_f32(float x) {
  float t;
  t = __uint_as_float((u32)__builtin_amdgcn_update_dpp((int)__float_as_uint(x),(int)__float_as_uint(x),0x0B1,0xF,0xF,false)); x += t;
  t = __uint_as_float((u32)__builtin_amdgcn_update_dpp((int)__float_as_uint(x),(int)__float_as_uint(x),0x04E,0xF,0xF,false)); x += t;
  t = __uint_as_float((u32)__builtin_amdgcn_update_dpp((int)__float_as_uint(x),(int)__float_as_uint(x),0x141,0xF,0xF,false)); x += t;
  t = __uint_as_float((u32)__builtin_amdgcn_update_dpp((int)__float_as_uint(x),(int)__float_as_uint(x),0x140,0xF,0xF,false)); x += t;
  return x;
}

// ---------------- Kernel A: bearing quaternions + |q|^2 prepack ----------------
__global__ __launch_bounds__(256) void kA_bearing(const float4* __restrict__ pts,
                                                  float4* __restrict__ bq,
                                                  float4* __restrict__ pts2) {
  int bf = blockIdx.x;                // b*F + f
  const float4* base = pts + (size_t)bf * P_;
  int tid = threadIdx.x;
  float x[8], y[8], z[8];
  float mnx =  INFINITY, mny =  INFINITY, mnz =  INFINITY;
  float mxx = -INFINITY, mxy = -INFINITY, mxz = -INFINITY;
#pragma unroll
  for (int i = 0; i < 8; ++i) {
    float4 v = base[tid + i*256];
    x[i]=v.x; y[i]=v.y; z[i]=v.z;
    mnx=fminf(mnx,v.x); mny=fminf(mny,v.y); mnz=fminf(mnz,v.z);
    mxx=fmaxf(mxx,v.x); mxy=fmaxf(mxy,v.y); mxz=fmaxf(mxz,v.z);
  }
#pragma unroll
  for (int off = 32; off >= 1; off >>= 1) {
    mnx=fminf(mnx,__shfl_xor(mnx,off)); mny=fminf(mny,__shfl_xor(mny,off)); mnz=fminf(mnz,__shfl_xor(mnz,off));
    mxx=fmaxf(mxx,__shfl_xor(mxx,off)); mxy=fmaxf(mxy,__shfl_xor(mxy,off)); mxz=fmaxf(mxz,__shfl_xor(mxz,off));
  }
  __shared__ float red[4][6];
  int wid = tid >> 6, lane = tid & 63;
  if (lane == 0) { red[wid][0]=mnx; red[wid][1]=mny; red[wid][2]=mnz;
                   red[wid][3]=mxx; red[wid][4]=mxy; red[wid][5]=mxz; }
  __syncthreads();
  mnx=fminf(fminf(red[0][0],red[1][0]),fminf(red[2][0],red[3][0]));
  mny=fminf(fminf(red[0][1],red[1][1]),fminf(red[2][1],red[3][1]));
  mnz=fminf(fminf(red[0][2],red[1][2]),fminf(red[2][2],red[3][2]));
  mxx=fmaxf(fmaxf(red[0][3],red[1][3]),fmaxf(red[2][3],red[3][3]));
  mxy=fmaxf(fmaxf(red[0][4],red[1][4]),fmaxf(red[2][4],red[3][4]));
  mxz=fmaxf(fmaxf(red[0][5],red[1][5]),fmaxf(red[2][5],red[3][5]));
  float cx=(mnx+mxx)*0.5f, cy=(mny+mxy)*0.5f, cz=(mnz+mxz)*0.5f;
#pragma unroll
  for (int i = 0; i < 8; ++i) {
    float dx=x[i]-cx, dy=y[i]-cy, dz=z[i]-cz;
    float n = sqrtf(((dx*dx) + dy*dy) + dz*dz);
    n = fmaxf(n, 1e-12f);
    float dxn = dx/n, dyn = dy/n, dzn = dz/n;
    float dotc = fminf(fmaxf(dyn, -0.99999990f), 0.99999990f);
    float half = acosf(dotc) * 0.5f;
    float an = sqrtf(dzn*dzn + dxn*dxn);
    an = fmaxf(an, 1e-12f);
    float axx = dzn/an, axz = (-dxn)/an;
    float s = sinf(half), w = cosf(half);
    bq[(size_t)bf*P_ + tid + i*256] = make_float4(w, axx*s, 0.f, axz*s);
    float qs = fmaf(x[i],x[i], fmaf(y[i],y[i], z[i]*z[i]));
    pts2[(size_t)bf*P_ + tid + i*256] = make_float4(x[i], y[i], z[i], qs);
  }
}

// ---------------- Kernel B: forward quaternions ----------------
__global__ __launch_bounds__(256) void kB_qfwd(const float4* __restrict__ bq,
                                               float4* __restrict__ qf) {
  int i = blockIdx.x*256 + threadIdx.x;   // over B*T*P
  int p = i & (P_-1);
  int t = (i >> 11) % T_;
  int b = i / (T_*P_);
  float4 s = bq[((size_t)(b*F_ + t))*P_ + p];       // frame t (src)
  float4 a = bq[((size_t)(b*F_ + t + 1))*P_ + p];   // frame t+1 (tgt)
  float aw=a.x, ax=a.y, ay=a.z, az=a.w;
  float bw=s.x, bx=-s.y, by=-s.z, bz=-s.w;          // conj
  float w  = ((aw*bw - ax*bx) - ay*by) - az*bz;
  float xo = ((aw*bx + ax*bw) + ay*bz) - az*by;
  float yo = ((aw*by - ax*bz) + ay*bw) + az*bx;
  float zo = ((aw*bz + ax*by) - ay*bx) + az*bw;
  float n = sqrtf(((w*w + xo*xo) + yo*yo) + zo*zo);
  n = fmaxf(n, 1e-12f);
  qf[i] = make_float4(w/n, xo/n, yo/n, zo/n);
}

// ---------------- Kernel C: top-40, quarter-wave rows (4 rows/wave) ----------------
__device__ __forceinline__ double mkkey(float4 c, u32 q,
                                        float px, float py, float pz, float ps) {
  float dot = fmaf(px, c.x, fmaf(py, c.y, pz*c.z));
  float v = (2.f*dot - ps) - c.w;      // = reference neg_dist
  float nd = -v;                       // ascending distance
  u32 u = __float_as_uint(nd);
  u32 ou = (u & 0x80000000u) ? ~u : (u | 0x80000000u);
  return __longlong_as_double((long long)(0x4000000000000000ull | ((u64)ou << 16) | q));
}

// one pop of the 4-rows-per-wave stream (each 16-lane quarter owns a row)
__device__ __forceinline__ void popstep(u32 (&OU)[8], u32 (&IX)[8],
                                        u32& LOU, u32& LIX, u32& CAP, int imod,
                                        int slot, const float4* __restrict__ pbase,
                                        float px, float py, float pz, float ps) {
  if (__any(OU[0] == SENT_OU)) {       // exact refill, cold (P ~ 0.06%/lane-row)
    bool need = (OU[0] == SENT_OU);
    u64 lastK = ((u64)LOU << 16) | LIX;
    u64 best = ~0ull;
    for (int j = 0; j < 128; ++j) {
      u32 q = (u32)(j*16 + slot);
      float4 c = pbase[q];
      float dot = fmaf(px, c.x, fmaf(py, c.y, pz*c.z));
      float v = (2.f*dot - ps) - c.w;
      u32 u = __float_as_uint(-v);
      u32 ou = (u & 0x80000000u) ? ~u : (u | 0x80000000u);
      u64 kk = ((u64)ou << 16) | q;
      if (kk > lastK && kk < best) best = kk;
    }
    if (need && best != ~0ull) { OU[0] = (u32)(best >> 16); IX[0] = (u32)(best & 0xffffu); }
  }
  u32 qmin = bfly16_min_u32(OU[0]);                  // all lanes get quarter min ou
  bool meq = (OU[0] == qmin);
  u32 tt   = meq ? IX[0] : 0xFFFFFFFFu;
  u32 widx = bfly16_min_u32(tt);                     // exact idx tie-break, all lanes
  bool iam = meq && (IX[0] == widx);
  CAP = (slot == imod) ? widx : CAP;
  LOU = iam ? qmin : LOU;
  LIX = iam ? widx : LIX;
#pragma unroll
  for (int jj = 0; jj < 7; ++jj) {
    OU[jj] = iam ? OU[jj+1] : OU[jj];
    IX[jj] = iam ? IX[jj+1] : IX[jj];
  }
  OU[7] = iam ? SENT_OU : OU[7];
}

__global__ __launch_bounds__(64) void kC_select(const float4* __restrict__ pts2,
                                                const float4* __restrict__ qf,
                                                float* __restrict__ S) {
  int lane = threadIdx.x;
  int slot = lane & 15;                // position within 16-lane quarter
  int quarter = lane >> 4;             // 0..3
  int p0 = (blockIdx.x * 4) & (P_-1);  // 4 consecutive rows, same tile
  int bt = (blockIdx.x * 4) >> 11;     // b*7 + t
  int t  = bt % T_;
  int b  = bt / T_;
  const float4* pbase = pts2 + (size_t)(b*F_ + t) * P_;

  int prow = p0 + quarter;             // this quarter's row
  float4 pw = pbase[prow];
  float px=pw.x, py=pw.y, pz=pw.z, ps=pw.w;

  // ---- sort phase: per lane 128 candidates (j*16+slot), keep sorted top-8 ----
  double acc[8];
#pragma unroll
  for (int j = 0; j < 8; ++j) acc[j] = __builtin_huge_val();
#pragma unroll 2
  for (int batch = 0; batch < 16; ++batch) {
    int qb = batch*128 + slot;
    float4 c[8];
#pragma unroll
    for (int u = 0; u < 8; ++u) c[u] = pbase[qb + u*16];
    double k[8];
#pragma unroll
    for (int u = 0; u < 8; ++u) k[u] = mkkey(c[u], (u32)(qb + u*16), px,py,pz,ps);
    sort8d(k);
    low8(acc, k);
  }

  // unpack into register queue
  u32 OU[8], IX[8];
#pragma unroll
  for (int j = 0; j < 8; ++j) {
    u64 bb = (u64)__double_as_longlong(acc[j]);
    OU[j] = (u32)(bb >> 16); IX[j] = (u32)(bb & 0xffffu);
  }

  u32 lou=0, lix=0, cap1=0, cap2=0, cap3=0;

#pragma unroll 1
  for (int i = 0; i < 16; ++i)         // winners 0..15 -> cap1[slot==i]
    popstep(OU, IX, lou, lix, cap1, i, slot, pbase, px,py,pz,ps);
#pragma unroll 1
  for (int i = 0; i < 16; ++i)         // winners 16..31 -> cap2
    popstep(OU, IX, lou, lix, cap2, i, slot, pbase, px,py,pz,ps);
#pragma unroll 1
  for (int i = 0; i < 8; ++i)          // winners 32..39 -> cap3 (slots 0..7)
    popstep(OU, IX, lou, lix, cap3, i, slot, pbase, px,py,pz,ps);

  // ---- epilogue: geodesic sums ----
  int row = bt*P_ + prow;
  const float4* qbt = qf + (size_t)bt * P_;
  float4 qp = qf[row];

  float4 n; float d;
  n = qbt[cap1]; d = ((qp.x*n.x + qp.y*n.y) + qp.z*n.z) + qp.w*n.w;
  float g1 = 2.f * acosf(fminf(fabsf(d), 0.99999990f));
  n = qbt[cap2]; d = ((qp.x*n.x + qp.y*n.y) + qp.z*n.z) + qp.w*n.w;
  float g2 = 2.f * acosf(fminf(fabsf(d), 0.99999990f));
  n = qbt[cap3]; d = ((qp.x*n.x + qp.y*n.y) + qp.z*n.z) + qp.w*n.w;
  float g3 = (slot < 8) ? 2.f * acosf(fminf(fabsf(d), 0.99999990f)) : 0.f;

  float s40 = bfly16_sum_f32(g1 + g2 + g3);
  float s15 = bfly16_sum_f32((slot < 15) ? g1 : 0.f);
  float s5  = bfly16_sum_f32((slot < 5)  ? g1 : 0.f);

  if (slot == 0) {
    S[0*ROWS + row] = s5  / 5.f;
    S[1*ROWS + row] = s15 / 15.f;
    S[2*ROWS + row] = s40 / 40.f;
  }
}

// ---------------- Kernel E: mean over t, median, output ----------------
__global__ __launch_bounds__(1024) void kE_final(const float* __restrict__ S,
                                                 float* __restrict__ out) {
  int k = blockIdx.x;                  // scale index 0..2
  int tid = threadIdx.x;
  __shared__ float srt[4096];
  const float* Sk = S + (size_t)k * ROWS;
  float m[4];
#pragma unroll
  for (int u = 0; u < 4; ++u) {
    int j = tid + u*1024;              // j = b*2048 + p
    int b = j >> 11, p = j & 2047;
    float acc = 0.f;
#pragma unroll
    for (int t = 0; t < 7; ++t) acc += Sk[(b*7 + t)*2048 + p];
    m[u] = acc / 7.f;
    srt[j] = m[u];
  }
  __syncthreads();
  for (int size = 2; size <= 4096; size <<= 1) {
    for (int stride = size >> 1; stride > 0; stride >>= 1) {
      for (int c = tid; c < 2048; c += 1024) {
        int i = 2*c - (c & (stride - 1));
        int j = i + stride;
        bool up = ((i & size) == 0);
        float a = srt[i], bb = srt[j];
        if ((a > bb) == up) { srt[i] = bb; srt[j] = a; }
      }
      __syncthreads();
    }
  }
  float scale = fmaxf(srt[2047], 1e-6f);   // lower median of 4096
  bool pos = srt[4095] > 0.f;
#pragma unroll
  for (int u = 0; u < 4; ++u) {
    int j = tid + u*1024;
    int b = j >> 11, p = j & 2047;
    float r = pos ? expf(-m[u]/scale) : 1.f;
    float* ob = out + ((size_t)(b*3 + k)*8)*2048 + p;
#pragma unroll
    for (int f = 0; f < 8; ++f) ob[f*2048] = r;
  }
}

extern "C" void kernel_launch(void* const* d_in, const int* in_sizes, int n_in,
                              void* d_out, int out_size, void* d_ws, size_t ws_size,
                              hipStream_t stream) {
  (void)in_sizes; (void)n_in; (void)out_size; (void)ws_size;
  const float4* pts = (const float4*)d_in[0];
  float* ws = (float*)d_ws;
  float4* bq   = (float4*)ws;                     // B*F*P*4   = 131072 floats
  float4* qfw  = (float4*)(ws + 131072);          // B*T*P*4   = 114688 floats
  float*  S    = ws + 131072 + 114688;            // 3*ROWS    =  86016 floats
  float4* pts2 = (float4*)(ws + 131072 + 114688 + 86016);  // B*F*P*4 = 131072 floats
  float*  out = (float*)d_out;

  hipLaunchKernelGGL(kA_bearing, dim3(B_*F_), dim3(256), 0, stream, pts, bq, pts2);
  hipLaunchKernelGGL(kB_qfwd,    dim3(ROWS/256), dim3(256), 0, stream, bq, qfw);
  hipLaunchKernelGGL(kC_select,  dim3(ROWS/4), dim3(64), 0, stream, pts2, qfw, S);
  hipLaunchKernelGGL(kE_final,   dim3(3), dim3(1024), 0, stream, S, out);
}

// Round 7
// 142.554 us; speedup vs baseline: 2.1700x; 1.0059x over previous
//
#include <hip/hip_runtime.h>
#include <math.h>

typedef unsigned long long u64;
typedef unsigned int u32;

#define B_ 2
#define F_ 8
#define P_ 2048
#define T_ 7                   // F-1
#define ROWS (B_*T_*P_)        // 28672
#define SENT_OU 0xFFFFFFFFu

// ---- keys as positive-normal doubles: bit pattern 0x4000.. | ou<<16 | idx ----
// positive doubles: IEEE ordering == integer ordering -> CE = v_min_f64+v_max_f64
#define CED(arr,a,b) do { double _x=arr[a], _y=arr[b]; arr[a]=fmin(_x,_y); arr[b]=fmax(_x,_y); } while(0)

// Batcher odd-even mergesort, 8 elements, 19 comparators
__device__ __forceinline__ void sort8d(double* k) {
  CED(k,0,1); CED(k,2,3); CED(k,4,5); CED(k,6,7);
  CED(k,0,2); CED(k,1,3); CED(k,4,6); CED(k,5,7);
  CED(k,1,2); CED(k,5,6);
  CED(k,0,4); CED(k,1,5); CED(k,2,6); CED(k,3,7);
  CED(k,2,4); CED(k,3,5);
  CED(k,1,2); CED(k,3,4); CED(k,5,6);
}

// A,B sorted ascending -> A = lowest 8 of the 16, sorted
__device__ __forceinline__ void low8(double* A, const double* Bv) {
#pragma unroll
  for (int i = 0; i < 8; ++i) A[i] = fmin(A[i], Bv[7-i]);   // bitonic
#pragma unroll
  for (int st = 4; st >= 1; st >>= 1) {
#pragma unroll
    for (int i = 0; i < 8; ++i) {
      if ((i & st) == 0) { CED(A, i, i + st); }
    }
  }
}

// ---- quarter(16-lane)-local butterfly reductions via DPP: result in ALL lanes ----
__device__ __forceinline__ u32 bfly16_min_u32(u32 x) {
  u32 t;
  t = (u32)__builtin_amdgcn_update_dpp((int)x,(int)x,0x0B1,0xF,0xF,false); x = t<x?t:x;
  t = (u32)__builtin_amdgcn_update_dpp((int)x,(int)x,0x04E,0xF,0xF,false); x = t<x?t:x;
  t = (u32)__builtin_amdgcn_update_dpp((int)x,(int)x,0x141,0xF,0xF,false); x = t<x?t:x;
  t = (u32)__builtin_amdgcn_update_dpp((int)x,(int)x,0x140,0xF,0xF,false); x = t<x?t:x;
  return x;
}
__device__ __forceinline__ float bfly16_sum_f32(float x) {
  float t;
  t = __uint_as_float((u32)__builtin_amdgcn_update_dpp((int)__float_as_uint(x),(int)__float_as_uint(x),0x0B1,0xF,0xF,false)); x += t;
  t = __uint_as_float((u32)__builtin_amdgcn_update_dpp((int)__float_as_uint(x),(int)__float_as_uint(x),0x04E,0xF,0xF,false)); x += t;
  t = __uint_as_float((u32)__builtin_amdgcn_update_dpp((int)__float_as_uint(x),(int)__float_as_uint(x),0x141,0xF,0xF,false)); x += t;
  t = __uint_as_float((u32)__builtin_amdgcn_update_dpp((int)__float_as_uint(x),(int)__float_as_uint(x),0x140,0xF,0xF,false)); x += t;
  return x;
}

// ---------------- Kernel A: bearing quaternions + |q|^2 prepack ----------------
__global__ __launch_bounds__(256) void kA_bearing(const float4* __restrict__ pts,
                                                  float4* __restrict__ bq,
                                                  float4* __restrict__ pts2) {
  int bf = blockIdx.x;                // b*F + f
  const float4* base = pts + (size_t)bf * P_;
  int tid = threadIdx.x;
  float x[8], y[8], z[8];
  float mnx =  INFINITY, mny =  INFINITY, mnz =  INFINITY;
  float mxx = -INFINITY, mxy = -INFINITY, mxz = -INFINITY;
#pragma unroll
  for (int i = 0; i < 8; ++i) {
    float4 v = base[tid + i*256];
    x[i]=v.x; y[i]=v.y; z[i]=v.z;
    mnx=fminf(mnx,v.x); mny=fminf(mny,v.y); mnz=fminf(mnz,v.z);
    mxx=fmaxf(mxx,v.x); mxy=fmaxf(mxy,v.y); mxz=fmaxf(mxz,v.z);
  }
#pragma unroll
  for (int off = 32; off >= 1; off >>= 1) {
    mnx=fminf(mnx,__shfl_xor(mnx,off)); mny=fminf(mny,__shfl_xor(mny,off)); mnz=fminf(mnz,__shfl_xor(mnz,off));
    mxx=fmaxf(mxx,__shfl_xor(mxx,off)); mxy=fmaxf(mxy,__shfl_xor(mxy,off)); mxz=fmaxf(mxz,__shfl_xor(mxz,off));
  }
  __shared__ float red[4][6];
  int wid = tid >> 6, lane = tid & 63;
  if (lane == 0) { red[wid][0]=mnx; red[wid][1]=mny; red[wid][2]=mnz;
                   red[wid][3]=mxx; red[wid][4]=mxy; red[wid][5]=mxz; }
  __syncthreads();
  mnx=fminf(fminf(red[0][0],red[1][0]),fminf(red[2][0],red[3][0]));
  mny=fminf(fminf(red[0][1],red[1][1]),fminf(red[2][1],red[3][1]));
  mnz=fminf(fminf(red[0][2],red[1][2]),fminf(red[2][2],red[3][2]));
  mxx=fmaxf(fmaxf(red[0][3],red[1][3]),fmaxf(red[2][3],red[3][3]));
  mxy=fmaxf(fmaxf(red[0][4],red[1][4]),fmaxf(red[2][4],red[3][4]));
  mxz=fmaxf(fmaxf(red[0][5],red[1][5]),fmaxf(red[2][5],red[3][5]));
  float cx=(mnx+mxx)*0.5f, cy=(mny+mxy)*0.5f, cz=(mnz+mxz)*0.5f;
#pragma unroll
  for (int i = 0; i < 8; ++i) {
    float dx=x[i]-cx, dy=y[i]-cy, dz=z[i]-cz;
    float n = sqrtf(((dx*dx) + dy*dy) + dz*dz);
    n = fmaxf(n, 1e-12f);
    float dxn = dx/n, dyn = dy/n, dzn = dz/n;
    float dotc = fminf(fmaxf(dyn, -0.99999990f), 0.99999990f);
    float half = acosf(dotc) * 0.5f;
    float an = sqrtf(dzn*dzn + dxn*dxn);
    an = fmaxf(an, 1e-12f);
    float axx = dzn/an, axz = (-dxn)/an;
    float s = sinf(half), w = cosf(half);
    bq[(size_t)bf*P_ + tid + i*256] = make_float4(w, axx*s, 0.f, axz*s);
    float qs = fmaf(x[i],x[i], fmaf(y[i],y[i], z[i]*z[i]));
    pts2[(size_t)bf*P_ + tid + i*256] = make_float4(x[i], y[i], z[i], qs);
  }
}

// ---------------- Kernel B: forward quaternions ----------------
__global__ __launch_bounds__(256) void kB_qfwd(const float4* __restrict__ bq,
                                               float4* __restrict__ qf) {
  int i = blockIdx.x*256 + threadIdx.x;   // over B*T*P
  int p = i & (P_-1);
  int t = (i >> 11) % T_;
  int b = i / (T_*P_);
  float4 s = bq[((size_t)(b*F_ + t))*P_ + p];       // frame t (src)
  float4 a = bq[((size_t)(b*F_ + t + 1))*P_ + p];   // frame t+1 (tgt)
  float aw=a.x, ax=a.y, ay=a.z, az=a.w;
  float bw=s.x, bx=-s.y, by=-s.z, bz=-s.w;          // conj
  float w  = ((aw*bw - ax*bx) - ay*by) - az*bz;
  float xo = ((aw*bx + ax*bw) + ay*bz) - az*by;
  float yo = ((aw*by - ax*bz) + ay*bw) + az*bx;
  float zo = ((aw*bz + ax*by) - ay*bx) + az*bw;
  float n = sqrtf(((w*w + xo*xo) + yo*yo) + zo*zo);
  n = fmaxf(n, 1e-12f);
  qf[i] = make_float4(w/n, xo/n, yo/n, zo/n);
}

// ---------------- Kernel C: top-40, quarter-wave rows, 4 waves/block ----------------
__device__ __forceinline__ double mkkey(float4 c, u32 q,
                                        float px, float py, float pz, float ps) {
  float dot = fmaf(px, c.x, fmaf(py, c.y, pz*c.z));
  float v = (2.f*dot - ps) - c.w;      // = reference neg_dist
  float nd = -v;                       // ascending distance
  u32 u = __float_as_uint(nd);
  u32 ou = (u & 0x80000000u) ? ~u : (u | 0x80000000u);
  return __longlong_as_double((long long)(0x4000000000000000ull | ((u64)ou << 16) | q));
}

// one pop of the 4-rows-per-wave stream (each 16-lane quarter owns a row)
__device__ __forceinline__ void popstep(u32 (&OU)[8], u32 (&IX)[8],
                                        u32& LOU, u32& LIX, u32& CAP, int imod,
                                        int slot, const float4* __restrict__ pbase,
                                        float px, float py, float pz, float ps) {
  if (__any(OU[0] == SENT_OU)) {       // exact refill, cold (P ~ 0.07%/lane-row)
    bool need = (OU[0] == SENT_OU);
    u64 lastK = ((u64)LOU << 16) | LIX;
    u64 best = ~0ull;
    for (int j = 0; j < 128; ++j) {
      u32 q = (u32)(j*16 + slot);
      float4 c = pbase[q];
      float dot = fmaf(px, c.x, fmaf(py, c.y, pz*c.z));
      float v = (2.f*dot - ps) - c.w;
      u32 u = __float_as_uint(-v);
      u32 ou = (u & 0x80000000u) ? ~u : (u | 0x80000000u);
      u64 kk = ((u64)ou << 16) | q;
      if (kk > lastK && kk < best) best = kk;
    }
    if (need && best != ~0ull) { OU[0] = (u32)(best >> 16); IX[0] = (u32)(best & 0xffffu); }
  }
  u32 qmin = bfly16_min_u32(OU[0]);                  // all lanes get quarter min ou
  bool meq = (OU[0] == qmin);
  u32 tt   = meq ? IX[0] : 0xFFFFFFFFu;
  u32 widx = bfly16_min_u32(tt);                     // exact idx tie-break, all lanes
  bool iam = meq && (IX[0] == widx);
  CAP = (slot == imod) ? widx : CAP;
  LOU = iam ? qmin : LOU;
  LIX = iam ? widx : LIX;
#pragma unroll
  for (int jj = 0; jj < 7; ++jj) {
    OU[jj] = iam ? OU[jj+1] : OU[jj];
    IX[jj] = iam ? IX[jj+1] : IX[jj];
  }
  OU[7] = iam ? SENT_OU : OU[7];
}

__global__ __launch_bounds__(256) void kC_select(const float4* __restrict__ pts2,
                                                 const float4* __restrict__ qf,
                                                 float* __restrict__ S) {
  int lane = threadIdx.x & 63;
  int wid  = threadIdx.x >> 6;         // wave within block (0..3)
  int slot = lane & 15;                // position within 16-lane quarter
  int quarter = lane >> 4;             // 0..3
  int gid = blockIdx.x * 16 + wid * 4; // first row of this wave
  int p0 = gid & (P_-1);               // 16 divides 2048 -> same tile across waves
  int bt = gid >> 11;                  // b*7 + t
  int t  = bt % T_;
  int b  = bt / T_;
  const float4* pbase = pts2 + (size_t)(b*F_ + t) * P_;

  int prow = p0 + quarter;             // this quarter's row
  float4 pw = pbase[prow];
  float px=pw.x, py=pw.y, pz=pw.z, ps=pw.w;

  // ---- sort phase: per lane 128 candidates (j*16+slot), keep sorted top-8 ----
  double acc[8];
#pragma unroll
  for (int j = 0; j < 8; ++j) acc[j] = __builtin_huge_val();
#pragma unroll 2
  for (int batch = 0; batch < 16; ++batch) {
    int qb = batch*128 + slot;
    float4 c[8];
#pragma unroll
    for (int u = 0; u < 8; ++u) c[u] = pbase[qb + u*16];
    double k[8];
#pragma unroll
    for (int u = 0; u < 8; ++u) k[u] = mkkey(c[u], (u32)(qb + u*16), px,py,pz,ps);
    sort8d(k);
    low8(acc, k);
  }

  // unpack into register queue
  u32 OU[8], IX[8];
#pragma unroll
  for (int j = 0; j < 8; ++j) {
    u64 bb = (u64)__double_as_longlong(acc[j]);
    OU[j] = (u32)(bb >> 16); IX[j] = (u32)(bb & 0xffffu);
  }

  u32 lou=0, lix=0, cap1=0, cap2=0, cap3=0;

#pragma unroll 1
  for (int i = 0; i < 16; ++i)         // winners 0..15 -> cap1[slot==i]
    popstep(OU, IX, lou, lix, cap1, i, slot, pbase, px,py,pz,ps);
#pragma unroll 1
  for (int i = 0; i < 16; ++i)         // winners 16..31 -> cap2
    popstep(OU, IX, lou, lix, cap2, i, slot, pbase, px,py,pz,ps);
#pragma unroll 1
  for (int i = 0; i < 8; ++i)          // winners 32..39 -> cap3 (slots 0..7)
    popstep(OU, IX, lou, lix, cap3, i, slot, pbase, px,py,pz,ps);

  // ---- epilogue: geodesic sums ----
  int row = bt*P_ + prow;
  const float4* qbt = qf + (size_t)bt * P_;
  float4 qp = qf[row];

  float4 n; float d;
  n = qbt[cap1]; d = ((qp.x*n.x + qp.y*n.y) + qp.z*n.z) + qp.w*n.w;
  float g1 = 2.f * acosf(fminf(fabsf(d), 0.99999990f));
  n = qbt[cap2]; d = ((qp.x*n.x + qp.y*n.y) + qp.z*n.z) + qp.w*n.w;
  float g2 = 2.f * acosf(fminf(fabsf(d), 0.99999990f));
  n = qbt[cap3]; d = ((qp.x*n.x + qp.y*n.y) + qp.z*n.z) + qp.w*n.w;
  float g3 = (slot < 8) ? 2.f * acosf(fminf(fabsf(d), 0.99999990f)) : 0.f;

  float s40 = bfly16_sum_f32(g1 + g2 + g3);
  float s15 = bfly16_sum_f32((slot < 15) ? g1 : 0.f);
  float s5  = bfly16_sum_f32((slot < 5)  ? g1 : 0.f);

  if (slot == 0) {
    S[0*ROWS + row] = s5  / 5.f;
    S[1*ROWS + row] = s15 / 15.f;
    S[2*ROWS + row] = s40 / 40.f;
  }
}

// ---------------- Kernel E: mean over t, median, output ----------------
__global__ __launch_bounds__(1024) void kE_final(const float* __restrict__ S,
                                                 float* __restrict__ out) {
  int k = blockIdx.x;                  // scale index 0..2
  int tid = threadIdx.x;
  __shared__ float srt[4096];
  const float* Sk = S + (size_t)k * ROWS;
  float m[4];
#pragma unroll
  for (int u = 0; u < 4; ++u) {
    int j = tid + u*1024;              // j = b*2048 + p
    int b = j >> 11, p = j & 2047;
    float acc = 0.f;
#pragma unroll
    for (int t = 0; t < 7; ++t) acc += Sk[(b*7 + t)*2048 + p];
    m[u] = acc / 7.f;
    srt[j] = m[u];
  }
  __syncthreads();
  for (int size = 2; size <= 4096; size <<= 1) {
    for (int stride = size >> 1; stride > 0; stride >>= 1) {
      for (int c = tid; c < 2048; c += 1024) {
        int i = 2*c - (c & (stride - 1));
        int j = i + stride;
        bool up = ((i & size) == 0);
        float a = srt[i], bb = srt[j];
        if ((a > bb) == up) { srt[i] = bb; srt[j] = a; }
      }
      __syncthreads();
    }
  }
  float scale = fmaxf(srt[2047], 1e-6f);   // lower median of 4096
  bool pos = srt[4095] > 0.f;
#pragma unroll
  for (int u = 0; u < 4; ++u) {
    int j = tid + u*1024;
    int b = j >> 11, p = j & 2047;
    float r = pos ? expf(-m[u]/scale) : 1.f;
    float* ob = out + ((size_t)(b*3 + k)*8)*2048 + p;
#pragma unroll
    for (int f = 0; f < 8; ++f) ob[f*2048] = r;
  }
}

extern "C" void kernel_launch(void* const* d_in, const int* in_sizes, int n_in,
                              void* d_out, int out_size, void* d_ws, size_t ws_size,
                              hipStream_t stream) {
  (void)in_sizes; (void)n_in; (void)out_size; (void)ws_size;
  const float4* pts = (const float4*)d_in[0];
  float* ws = (float*)d_ws;
  float4* bq   = (float4*)ws;                     // B*F*P*4   = 131072 floats
  float4* qfw  = (float4*)(ws + 131072);          // B*T*P*4   = 114688 floats
  float*  S    = ws + 131072 + 114688;            // 3*ROWS    =  86016 floats
  float4* pts2 = (float4*)(ws + 131072 + 114688 + 86016);  // B*F*P*4 = 131072 floats
  float*  out = (float*)d_out;

  hipLaunchKernelGGL(kA_bearing, dim3(B_*F_), dim3(256), 0, stream, pts, bq, pts2);
  hipLaunchKernelGGL(kB_qfwd,    dim3(ROWS/256), dim3(256), 0, stream, bq, qfw);
  hipLaunchKernelGGL(kC_select,  dim3(ROWS/16), dim3(256), 0, stream, pts2, qfw, S);
  hipLaunchKernelGGL(kE_final,   dim3(3), dim3(1024), 0, stream, S, out);
}